// Round 1
// baseline (1577.955 us; speedup 1.0000x reference)
//
#include <hip/hip_runtime.h>

#define NE 400000
#define NNODES 25000

// ---------------------------------------------------------------- zero agg
__global__ __launch_bounds__(256) void kzero(float4* __restrict__ p, int n4) {
  int i = blockIdx.x * 256 + threadIdx.x;
  if (i < n4) p[i] = make_float4(0.f, 0.f, 0.f, 0.f);
}

// ------------------------------------------- k1: w = x@W1/sqrt(128); scatter w*Y
__global__ __launch_bounds__(256) void k1_scatter(
    const float* __restrict__ x, const float* __restrict__ Y,
    const int* __restrict__ esrc, const float* __restrict__ W1,
    float* __restrict__ agg)
{
  __shared__ __align__(16) float W1s[128 * 32];
  __shared__ __align__(16) float xs[32][128];
  __shared__ __align__(16) float Ys[32][4];
  __shared__ int srcs[32];
  const int t = threadIdx.x;
  const int e0 = blockIdx.x * 32;

  for (int i = t; i < 1024; i += 256)
    *(float4*)&W1s[i * 4] = *(const float4*)&W1[i * 4];
  for (int i = t; i < 1024; i += 256) {
    int row = i >> 5, c = (i & 31) * 4;
    *(float4*)&xs[row][c] = *(const float4*)&x[(size_t)(e0 + row) * 128 + c];
  }
  if (t < 128) Ys[t >> 2][t & 3] = Y[e0 * 4 + t];
  if (t < 32) srcs[t] = esrc[e0 + t];
  __syncthreads();

  const int u = t & 31;
  const int es0 = t >> 5;
  float w[4] = {0.f, 0.f, 0.f, 0.f};
  #pragma unroll
  for (int k = 0; k < 128; k += 4) {
    float w0 = W1s[(k + 0) * 32 + u];
    float w1 = W1s[(k + 1) * 32 + u];
    float w2 = W1s[(k + 2) * 32 + u];
    float w3 = W1s[(k + 3) * 32 + u];
    #pragma unroll
    for (int j = 0; j < 4; ++j) {
      float4 xv = *(const float4*)&xs[es0 + j * 8][k];
      w[j] += xv.x * w0 + xv.y * w1 + xv.z * w2 + xv.w * w3;
    }
  }
  #pragma unroll
  for (int j = 0; j < 4; ++j) {
    int e = es0 + j * 8;
    float wv = w[j] * 0.08838834764831845f;  // 1/sqrt(128)
    float* ab = agg + (size_t)srcs[e] * 128 + u * 4;
    #pragma unroll
    for (int c = 0; c < 4; ++c)
      unsafeAtomicAdd(ab + c, wv * Ys[e][c]);
  }
}

// --------- k2: gather agg, tensor-product mix -> scalars (E,64) and V_out
__global__ __launch_bounds__(256) void k2_mix(
    const float* __restrict__ V, const int* __restrict__ esrc,
    const float* __restrict__ Wlin, const float* __restrict__ agg,
    float* __restrict__ scal, float* __restrict__ vout)
{
  __shared__ __align__(16) float Wls[64 * 32];
  __shared__ __align__(16) float Vv[8][64][4];
  __shared__ int srcs[8];
  const int t = threadIdx.x;
  const int e0 = blockIdx.x * 8;
  for (int i = t; i < 512; i += 256)
    *(float4*)&Wls[i * 4] = *(const float4*)&Wlin[i * 4];
  if (t < 8) srcs[t] = esrc[e0 + t];
  __syncthreads();

  const int sub = t >> 5, u = t & 31;
  const int e = e0 + sub;
  float4 a = *(const float4*)&agg[(size_t)srcs[sub] * 128 + u * 4];
  a.x *= 0.25f; a.y *= 0.25f; a.z *= 0.25f; a.w *= 0.25f;  // /sqrt(16)
  float4 b = *(const float4*)&V[(size_t)e * 128 + u * 4];
  float s1 = a.x * b.x;
  float s2 = (a.y * b.y + a.z * b.z + a.w * b.w) * 0.5773502691896258f;
  ((float2*)scal)[(size_t)e * 32 + u] = make_float2(s1, s2);
  Vv[sub][2 * u][0] = a.x * b.y;
  Vv[sub][2 * u][1] = a.x * b.z;
  Vv[sub][2 * u][2] = a.x * b.w;
  Vv[sub][2 * u + 1][0] = a.y * b.x;
  Vv[sub][2 * u + 1][1] = a.z * b.x;
  Vv[sub][2 * u + 1][2] = a.w * b.x;
  __syncthreads();

  float acc0 = 0.f, acc1 = 0.f, acc2 = 0.f;
  #pragma unroll 8
  for (int up = 0; up < 64; ++up) {
    float wl = Wls[up * 32 + u];
    float4 vv = *(const float4*)&Vv[sub][up][0];
    acc0 += vv.x * wl; acc1 += vv.y * wl; acc2 += vv.z * wl;
  }
  float* vp = vout + (size_t)e * 96 + u * 3;
  vp[0] = acc0 * 0.125f;   // 1/sqrt(64)
  vp[1] = acc1 * 0.125f;
  vp[2] = acc2 * 0.125f;
}

// ------------------------------------------------ tiled f32 GEMM (BM=128,BN=128,BK=16)
template <int K, bool SILU, bool CONCAT, bool ENV>
__global__ __launch_bounds__(256) void gemm_k(
    const float* __restrict__ A0, const float* __restrict__ A1,
    const float* __restrict__ B, const float* __restrict__ rvec,
    float* __restrict__ C, float scale)
{
  __shared__ __align__(16) float As[16][128];  // [k][row] (transposed)
  __shared__ __align__(16) float Bs[16][128];  // [k][col]
  const int t = threadIdx.x;
  const int e0 = blockIdx.x * 128;
  const int rg = t >> 4, cg = t & 15;
  const int ar = t >> 1, ak = (t & 1) * 8;
  const int bk = t >> 4, bc = (t & 15) * 8;

  float acc[8][8];
  #pragma unroll
  for (int i = 0; i < 8; ++i)
    #pragma unroll
    for (int j = 0; j < 8; ++j) acc[i][j] = 0.f;

  for (int kc = 0; kc < K; kc += 16) {
    float4 av0, av1, bv0, bv1;
    if (!CONCAT || (kc + ak) < 128) {
      const float* ap = A0 + (size_t)(e0 + ar) * (CONCAT ? 128 : K) + kc + ak;
      av0 = *(const float4*)ap;
      av1 = *(const float4*)(ap + 4);
    } else {
      const float* ap = A1 + (size_t)(e0 + ar) * 64 + (kc + ak - 128);
      av0 = *(const float4*)ap;
      av1 = *(const float4*)(ap + 4);
    }
    {
      const float* bp = B + (size_t)(kc + bk) * 128 + bc;
      bv0 = *(const float4*)bp;
      bv1 = *(const float4*)(bp + 4);
    }
    __syncthreads();
    As[ak + 0][ar] = av0.x;
    As[ak + 1][ar] = av0.y;
    As[ak + 2][ar] = av0.z;
    As[ak + 3][ar] = av0.w;
    As[ak + 4][ar] = av1.x;
    As[ak + 5][ar] = av1.y;
    As[ak + 6][ar] = av1.z;
    As[ak + 7][ar] = av1.w;
    *(float4*)&Bs[bk][bc] = bv0;
    *(float4*)&Bs[bk][bc + 4] = bv1;
    __syncthreads();
    #pragma unroll
    for (int k = 0; k < 16; ++k) {
      float a[8], b[8];
      *(float4*)&a[0] = *(const float4*)&As[k][rg * 8];
      *(float4*)&a[4] = *(const float4*)&As[k][rg * 8 + 4];
      *(float4*)&b[0] = *(const float4*)&Bs[k][cg * 8];
      *(float4*)&b[4] = *(const float4*)&Bs[k][cg * 8 + 4];
      #pragma unroll
      for (int i = 0; i < 8; ++i)
        #pragma unroll
        for (int j = 0; j < 8; ++j)
          acc[i][j] += a[i] * b[j];
    }
  }

  float envv[8];
  if (ENV) {
    #pragma unroll
    for (int i = 0; i < 8; ++i) {
      int row = e0 + rg * 8 + i;
      float rx = rvec[row * 3 + 0];
      float ry = rvec[row * 3 + 1];
      float rz = rvec[row * 3 + 2];
      float d2 = rx * rx + ry * ry + rz * rz;
      float d = (d2 == 0.f) ? 1.f : sqrtf(d2);
      float d3 = d * d * d;
      envv[i] = (d < 1.f) ? (1.f + d3 * d3 * (-28.f + d * (48.f - 21.f * d))) : 0.f;
    }
  }
  #pragma unroll
  for (int i = 0; i < 8; ++i) {
    int row = e0 + rg * 8 + i;
    float o[8];
    #pragma unroll
    for (int j = 0; j < 8; ++j) {
      float z = acc[i][j] * scale;
      if (SILU) z = z / (1.f + __expf(-z));
      if (ENV) z *= envv[i];
      o[j] = z;
    }
    float* cp = C + (size_t)row * 128 + cg * 8;
    *(float4*)cp = *(float4*)&o[0];
    *(float4*)(cp + 4) = *(float4*)&o[4];
  }
}

extern "C" void kernel_launch(void* const* d_in, const int* in_sizes, int n_in,
                              void* d_out, int out_size, void* d_ws, size_t ws_size,
                              hipStream_t stream)
{
  const float* x    = (const float*)d_in[0];
  const float* V    = (const float*)d_in[1];
  const float* r    = (const float*)d_in[2];
  const float* Y    = (const float*)d_in[3];
  const int*   es   = (const int*)d_in[4];
  const float* W1   = (const float*)d_in[5];
  const float* W2a  = (const float*)d_in[6];
  const float* W2b  = (const float*)d_in[7];
  const float* W2c  = (const float*)d_in[8];
  const float* Wlin = (const float*)d_in[9];

  float* ws   = (float*)d_ws;
  float* agg  = ws;                         // 3.2e6 floats (12.8 MB)
  float* scal = ws + 3200000;               // 25.6e6 floats (102.4 MB)
  float* h2   = ws;                         // 51.2e6 floats (reuses agg+scal, both dead)
  float* xout = (float*)d_out;              // 51.2e6 floats
  float* vout = (float*)d_out + 51200000;   // 38.4e6 floats
  float* h1   = xout;                       // stage h1 in x_out region (overwritten later)

  (void)in_sizes; (void)n_in; (void)out_size; (void)ws_size;

  kzero<<<dim3(3125), 256, 0, stream>>>((float4*)agg, 800000);
  k1_scatter<<<dim3(NE / 32), 256, 0, stream>>>(x, Y, es, W1, agg);
  k2_mix<<<dim3(NE / 8), 256, 0, stream>>>(V, es, Wlin, agg, scal, vout);
  // h1 = silu(concat(x, scal) @ W2a / sqrt(192))
  gemm_k<192, true,  true,  false><<<dim3(NE / 128), 256, 0, stream>>>(
      x, scal, W2a, nullptr, h1, 0.07216878364870323f);
  // h2 = silu(h1 @ W2b / sqrt(128))
  gemm_k<128, true,  false, false><<<dim3(NE / 128), 256, 0, stream>>>(
      h1, nullptr, W2b, nullptr, h2, 0.08838834764831845f);
  // x_out = env(d) * (h2 @ W2c / sqrt(128))
  gemm_k<128, false, false, true ><<<dim3(NE / 128), 256, 0, stream>>>(
      h2, nullptr, W2c, r, xout, 0.08838834764831845f);
}

// Round 2
// 1103.633 us; speedup vs baseline: 1.4298x; 1.4298x over previous
//
#include <hip/hip_runtime.h>

#define NE 400000
#define NNODES 25000

// ---------------------------------------------------- CSR build: histogram
__global__ __launch_bounds__(256) void khist(const int* __restrict__ esrc,
                                             int* __restrict__ cnt) {
  int e = blockIdx.x * 256 + threadIdx.x;
  if (e < NE) atomicAdd(&cnt[esrc[e]], 1);
}

// ------------------------------------- CSR build: exclusive scan (1 block)
__global__ __launch_bounds__(1024) void kscan(const int* __restrict__ cnt,
                                              int* __restrict__ start,
                                              int* __restrict__ cursor) {
  __shared__ int wsum[16];
  __shared__ int carry_s;
  const int t = threadIdx.x;
  const int lane = t & 63, wid = t >> 6;
  if (t == 0) carry_s = 0;
  __syncthreads();
  for (int base = 0; base < NNODES; base += 1024) {
    int idx = base + t;
    int v = (idx < NNODES) ? cnt[idx] : 0;
    int incl = v;
    #pragma unroll
    for (int off = 1; off < 64; off <<= 1) {
      int u = __shfl_up(incl, off, 64);
      if (lane >= off) incl += u;
    }
    if (lane == 63) wsum[wid] = incl;
    __syncthreads();
    if (wid == 0) {
      int wv = (lane < 16) ? wsum[lane] : 0;
      int wincl = wv;
      #pragma unroll
      for (int off = 1; off < 16; off <<= 1) {
        int u = __shfl_up(wincl, off, 64);
        if (lane >= off) wincl += u;
      }
      if (lane < 16) wsum[lane] = wincl - wv;  // exclusive wave offset
    }
    __syncthreads();
    int excl = incl - v + wsum[wid] + carry_s;
    if (idx < NNODES) { start[idx] = excl; cursor[idx] = excl; }
    __syncthreads();
    if (t == 1023) carry_s = excl + v;
    __syncthreads();
  }
  if (t == 0) start[NNODES] = carry_s;
}

// ---------------------------------------------------- CSR build: fill order
__global__ __launch_bounds__(256) void kfill(const int* __restrict__ esrc,
                                             int* __restrict__ cursor,
                                             int* __restrict__ order) {
  int e = blockIdx.x * 256 + threadIdx.x;
  if (e < NE) {
    int p = atomicAdd(&cursor[esrc[e]], 1);
    order[p] = e;
  }
}

// ----------------------------- k1w: w = x@W1/sqrt(128) -> wbuf (no atomics)
__global__ __launch_bounds__(256) void k1w(
    const float* __restrict__ x, const float* __restrict__ W1,
    float* __restrict__ wbuf)
{
  __shared__ __align__(16) float W1s[128 * 32];
  __shared__ __align__(16) float xs[32][128];
  const int t = threadIdx.x;
  const int e0 = blockIdx.x * 32;

  for (int i = t; i < 1024; i += 256)
    *(float4*)&W1s[i * 4] = *(const float4*)&W1[i * 4];
  for (int i = t; i < 1024; i += 256) {
    int row = i >> 5, c = (i & 31) * 4;
    *(float4*)&xs[row][c] = *(const float4*)&x[(size_t)(e0 + row) * 128 + c];
  }
  __syncthreads();

  const int u = t & 31;
  const int es0 = t >> 5;
  float w[4] = {0.f, 0.f, 0.f, 0.f};
  #pragma unroll
  for (int k = 0; k < 128; k += 4) {
    float w0 = W1s[(k + 0) * 32 + u];
    float w1 = W1s[(k + 1) * 32 + u];
    float w2 = W1s[(k + 2) * 32 + u];
    float w3 = W1s[(k + 3) * 32 + u];
    #pragma unroll
    for (int j = 0; j < 4; ++j) {
      float4 xv = *(const float4*)&xs[es0 + j * 8][k];
      w[j] += xv.x * w0 + xv.y * w1 + xv.z * w2 + xv.w * w3;
    }
  }
  #pragma unroll
  for (int j = 0; j < 4; ++j) {
    int e = es0 + j * 8;
    wbuf[(size_t)(e0 + e) * 32 + u] = w[j] * 0.08838834764831845f;  // 1/sqrt(128)
  }
}

// ------------------- k_agg: per-node gather reduction (1 wave per node)
__global__ __launch_bounds__(64) void k_agg(
    const float* __restrict__ wbuf, const float* __restrict__ Y,
    const int* __restrict__ start, const int* __restrict__ order,
    float* __restrict__ agg)
{
  const int n = blockIdx.x;
  const int t = threadIdx.x;
  const int c = t & 31;
  const int dh = t >> 5;  // 0 -> d={0,1}, 1 -> d={2,3}
  const int s0 = start[n], s1 = start[n + 1];
  float a0 = 0.f, a1 = 0.f;
  for (int i = s0; i < s1; ++i) {
    int e = order[i];
    float wv = wbuf[(size_t)e * 32 + c];
    float y0 = Y[e * 4 + dh * 2 + 0];
    float y1 = Y[e * 4 + dh * 2 + 1];
    a0 += wv * y0;
    a1 += wv * y1;
  }
  float* ap = agg + (size_t)n * 128 + c * 4 + dh * 2;
  ap[0] = a0;
  ap[1] = a1;
}

// --------- k2: gather agg, tensor-product mix -> scalars (E,64) and V_out
__global__ __launch_bounds__(256) void k2_mix(
    const float* __restrict__ V, const int* __restrict__ esrc,
    const float* __restrict__ Wlin, const float* __restrict__ agg,
    float* __restrict__ scal, float* __restrict__ vout)
{
  __shared__ __align__(16) float Wls[64 * 32];
  __shared__ __align__(16) float Vv[8][64][4];
  __shared__ int srcs[8];
  const int t = threadIdx.x;
  const int e0 = blockIdx.x * 8;
  for (int i = t; i < 512; i += 256)
    *(float4*)&Wls[i * 4] = *(const float4*)&Wlin[i * 4];
  if (t < 8) srcs[t] = esrc[e0 + t];
  __syncthreads();

  const int sub = t >> 5, u = t & 31;
  const int e = e0 + sub;
  float4 a = *(const float4*)&agg[(size_t)srcs[sub] * 128 + u * 4];
  a.x *= 0.25f; a.y *= 0.25f; a.z *= 0.25f; a.w *= 0.25f;  // /sqrt(16)
  float4 b = *(const float4*)&V[(size_t)e * 128 + u * 4];
  float s1 = a.x * b.x;
  float s2 = (a.y * b.y + a.z * b.z + a.w * b.w) * 0.5773502691896258f;
  ((float2*)scal)[(size_t)e * 32 + u] = make_float2(s1, s2);
  Vv[sub][2 * u][0] = a.x * b.y;
  Vv[sub][2 * u][1] = a.x * b.z;
  Vv[sub][2 * u][2] = a.x * b.w;
  Vv[sub][2 * u + 1][0] = a.y * b.x;
  Vv[sub][2 * u + 1][1] = a.z * b.x;
  Vv[sub][2 * u + 1][2] = a.w * b.x;
  __syncthreads();

  float acc0 = 0.f, acc1 = 0.f, acc2 = 0.f;
  #pragma unroll 8
  for (int up = 0; up < 64; ++up) {
    float wl = Wls[up * 32 + u];
    float4 vv = *(const float4*)&Vv[sub][up][0];
    acc0 += vv.x * wl; acc1 += vv.y * wl; acc2 += vv.z * wl;
  }
  float* vp = vout + (size_t)e * 96 + u * 3;
  vp[0] = acc0 * 0.125f;   // 1/sqrt(64)
  vp[1] = acc1 * 0.125f;
  vp[2] = acc2 * 0.125f;
}

// ------------------------------------------------ tiled f32 GEMM (BM=128,BN=128,BK=16)
template <int K, bool SILU, bool CONCAT, bool ENV>
__global__ __launch_bounds__(256) void gemm_k(
    const float* __restrict__ A0, const float* __restrict__ A1,
    const float* __restrict__ B, const float* __restrict__ rvec,
    float* __restrict__ C, float scale)
{
  __shared__ __align__(16) float As[16][128];  // [k][row] (transposed)
  __shared__ __align__(16) float Bs[16][128];  // [k][col]
  const int t = threadIdx.x;
  const int e0 = blockIdx.x * 128;
  const int rg = t >> 4, cg = t & 15;
  const int ar = t >> 1, ak = (t & 1) * 8;
  const int bk = t >> 4, bc = (t & 15) * 8;

  float acc[8][8];
  #pragma unroll
  for (int i = 0; i < 8; ++i)
    #pragma unroll
    for (int j = 0; j < 8; ++j) acc[i][j] = 0.f;

  for (int kc = 0; kc < K; kc += 16) {
    float4 av0, av1, bv0, bv1;
    if (!CONCAT || (kc + ak) < 128) {
      const float* ap = A0 + (size_t)(e0 + ar) * (CONCAT ? 128 : K) + kc + ak;
      av0 = *(const float4*)ap;
      av1 = *(const float4*)(ap + 4);
    } else {
      const float* ap = A1 + (size_t)(e0 + ar) * 64 + (kc + ak - 128);
      av0 = *(const float4*)ap;
      av1 = *(const float4*)(ap + 4);
    }
    {
      const float* bp = B + (size_t)(kc + bk) * 128 + bc;
      bv0 = *(const float4*)bp;
      bv1 = *(const float4*)(bp + 4);
    }
    __syncthreads();
    As[ak + 0][ar] = av0.x;
    As[ak + 1][ar] = av0.y;
    As[ak + 2][ar] = av0.z;
    As[ak + 3][ar] = av0.w;
    As[ak + 4][ar] = av1.x;
    As[ak + 5][ar] = av1.y;
    As[ak + 6][ar] = av1.z;
    As[ak + 7][ar] = av1.w;
    *(float4*)&Bs[bk][bc] = bv0;
    *(float4*)&Bs[bk][bc + 4] = bv1;
    __syncthreads();
    #pragma unroll
    for (int k = 0; k < 16; ++k) {
      float a[8], b[8];
      *(float4*)&a[0] = *(const float4*)&As[k][rg * 8];
      *(float4*)&a[4] = *(const float4*)&As[k][rg * 8 + 4];
      *(float4*)&b[0] = *(const float4*)&Bs[k][cg * 8];
      *(float4*)&b[4] = *(const float4*)&Bs[k][cg * 8 + 4];
      #pragma unroll
      for (int i = 0; i < 8; ++i)
        #pragma unroll
        for (int j = 0; j < 8; ++j)
          acc[i][j] += a[i] * b[j];
    }
  }

  float envv[8];
  if (ENV) {
    #pragma unroll
    for (int i = 0; i < 8; ++i) {
      int row = e0 + rg * 8 + i;
      float rx = rvec[row * 3 + 0];
      float ry = rvec[row * 3 + 1];
      float rz = rvec[row * 3 + 2];
      float d2 = rx * rx + ry * ry + rz * rz;
      float d = (d2 == 0.f) ? 1.f : sqrtf(d2);
      float d3 = d * d * d;
      envv[i] = (d < 1.f) ? (1.f + d3 * d3 * (-28.f + d * (48.f - 21.f * d))) : 0.f;
    }
  }
  #pragma unroll
  for (int i = 0; i < 8; ++i) {
    int row = e0 + rg * 8 + i;
    float o[8];
    #pragma unroll
    for (int j = 0; j < 8; ++j) {
      float z = acc[i][j] * scale;
      if (SILU) z = z / (1.f + __expf(-z));
      if (ENV) z *= envv[i];
      o[j] = z;
    }
    float* cp = C + (size_t)row * 128 + cg * 8;
    *(float4*)cp = *(float4*)&o[0];
    *(float4*)(cp + 4) = *(float4*)&o[4];
  }
}

extern "C" void kernel_launch(void* const* d_in, const int* in_sizes, int n_in,
                              void* d_out, int out_size, void* d_ws, size_t ws_size,
                              hipStream_t stream)
{
  const float* x    = (const float*)d_in[0];
  const float* V    = (const float*)d_in[1];
  const float* r    = (const float*)d_in[2];
  const float* Y    = (const float*)d_in[3];
  const int*   es   = (const int*)d_in[4];
  const float* W1   = (const float*)d_in[5];
  const float* W2a  = (const float*)d_in[6];
  const float* W2b  = (const float*)d_in[7];
  const float* W2c  = (const float*)d_in[8];
  const float* Wlin = (const float*)d_in[9];

  float* ws   = (float*)d_ws;
  float* agg  = ws;                          // [0, 3.2M) floats
  float* wbuf = ws + 3200000;                // [3.2M, 16M) — dead after k_agg
  float* scal = ws + 3200000;                // [3.2M, 28.8M) — overlays wbuf (written in k2, after k_agg)
  int*   ci   = (int*)(ws + 28800000);       // CSR ints
  int*   cnt    = ci;                        // 25000
  int*   startv = ci + 25000;                // 25001
  int*   cursor = ci + 50008;                // 25000
  int*   order  = ci + 75008;                // 400000
  float* h2   = ws;                          // [0, 51.2M) — overlays everything dead
  float* xout = (float*)d_out;
  float* vout = (float*)d_out + 51200000;
  float* h1   = xout;                        // staged in x_out region

  (void)in_sizes; (void)n_in; (void)out_size; (void)ws_size;

  hipMemsetAsync(cnt, 0, NNODES * sizeof(int), stream);
  khist<<<dim3((NE + 255) / 256), 256, 0, stream>>>(es, cnt);
  kscan<<<dim3(1), 1024, 0, stream>>>(cnt, startv, cursor);
  kfill<<<dim3((NE + 255) / 256), 256, 0, stream>>>(es, cursor, order);
  k1w<<<dim3(NE / 32), 256, 0, stream>>>(x, W1, wbuf);
  k_agg<<<dim3(NNODES), 64, 0, stream>>>(wbuf, Y, startv, order, agg);
  k2_mix<<<dim3(NE / 8), 256, 0, stream>>>(V, es, Wlin, agg, scal, vout);
  // h1 = silu(concat(x, scal) @ W2a / sqrt(192))
  gemm_k<192, true,  true,  false><<<dim3(NE / 128), 256, 0, stream>>>(
      x, scal, W2a, nullptr, h1, 0.07216878364870323f);
  // h2 = silu(h1 @ W2b / sqrt(128))
  gemm_k<128, true,  false, false><<<dim3(NE / 128), 256, 0, stream>>>(
      h1, nullptr, W2b, nullptr, h2, 0.08838834764831845f);
  // x_out = env(d) * (h2 @ W2c / sqrt(128))
  gemm_k<128, false, false, true ><<<dim3(NE / 128), 256, 0, stream>>>(
      h2, nullptr, W2c, r, xout, 0.08838834764831845f);
}

// Round 3
// 781.887 us; speedup vs baseline: 2.0181x; 1.4115x over previous
//
#include <hip/hip_runtime.h>

#define NE 400000
#define NNODES 25000

typedef __attribute__((ext_vector_type(8))) short short8;
typedef __attribute__((ext_vector_type(4))) float f32x4;

__device__ __forceinline__ unsigned short f2bf(float f) {
  unsigned int u = __float_as_uint(f);
  unsigned int r = u + 0x7fffu + ((u >> 16) & 1u);
  return (unsigned short)(r >> 16);
}
__device__ __forceinline__ float bf2f(unsigned short h) {
  return __uint_as_float(((unsigned int)h) << 16);
}

// ---------------------------------------------------- CSR build: histogram
__global__ __launch_bounds__(256) void khist(const int* __restrict__ esrc,
                                             int* __restrict__ cnt) {
  int e = blockIdx.x * 256 + threadIdx.x;
  if (e < NE) atomicAdd(&cnt[esrc[e]], 1);
}

// ------------------------------------- CSR build: exclusive scan (1 block)
__global__ __launch_bounds__(1024) void kscan(const int* __restrict__ cnt,
                                              int* __restrict__ start,
                                              int* __restrict__ cursor) {
  __shared__ int wsum[16];
  __shared__ int carry_s;
  const int t = threadIdx.x;
  const int lane = t & 63, wid = t >> 6;
  if (t == 0) carry_s = 0;
  __syncthreads();
  for (int base = 0; base < NNODES; base += 1024) {
    int idx = base + t;
    int v = (idx < NNODES) ? cnt[idx] : 0;
    int incl = v;
    #pragma unroll
    for (int off = 1; off < 64; off <<= 1) {
      int u = __shfl_up(incl, off, 64);
      if (lane >= off) incl += u;
    }
    if (lane == 63) wsum[wid] = incl;
    __syncthreads();
    if (wid == 0) {
      int wv = (lane < 16) ? wsum[lane] : 0;
      int wincl = wv;
      #pragma unroll
      for (int off = 1; off < 16; off <<= 1) {
        int u = __shfl_up(wincl, off, 64);
        if (lane >= off) wincl += u;
      }
      if (lane < 16) wsum[lane] = wincl - wv;
    }
    __syncthreads();
    int excl = incl - v + wsum[wid] + carry_s;
    if (idx < NNODES) { start[idx] = excl; cursor[idx] = excl; }
    __syncthreads();
    if (t == 1023) carry_s = excl + v;
    __syncthreads();
  }
  if (t == 0) start[NNODES] = carry_s;
}

// ---------------------------------------------------- CSR build: fill order
__global__ __launch_bounds__(256) void kfill(const int* __restrict__ esrc,
                                             int* __restrict__ cursor,
                                             int* __restrict__ order) {
  int e = blockIdx.x * 256 + threadIdx.x;
  if (e < NE) {
    int p = atomicAdd(&cursor[esrc[e]], 1);
    order[p] = e;
  }
}

// ----------------------------- k1w: w = x@W1/sqrt(128) -> wbuf (no atomics)
__global__ __launch_bounds__(256) void k1w(
    const float* __restrict__ x, const float* __restrict__ W1,
    float* __restrict__ wbuf)
{
  __shared__ __align__(16) float W1s[128 * 32];
  __shared__ __align__(16) float xs[32][128];
  const int t = threadIdx.x;
  const int e0 = blockIdx.x * 32;

  for (int i = t; i < 1024; i += 256)
    *(float4*)&W1s[i * 4] = *(const float4*)&W1[i * 4];
  for (int i = t; i < 1024; i += 256) {
    int row = i >> 5, c = (i & 31) * 4;
    *(float4*)&xs[row][c] = *(const float4*)&x[(size_t)(e0 + row) * 128 + c];
  }
  __syncthreads();

  const int u = t & 31;
  const int es0 = t >> 5;
  float w[4] = {0.f, 0.f, 0.f, 0.f};
  #pragma unroll
  for (int k = 0; k < 128; k += 4) {
    float w0 = W1s[(k + 0) * 32 + u];
    float w1 = W1s[(k + 1) * 32 + u];
    float w2 = W1s[(k + 2) * 32 + u];
    float w3 = W1s[(k + 3) * 32 + u];
    #pragma unroll
    for (int j = 0; j < 4; ++j) {
      float4 xv = *(const float4*)&xs[es0 + j * 8][k];
      w[j] += xv.x * w0 + xv.y * w1 + xv.z * w2 + xv.w * w3;
    }
  }
  #pragma unroll
  for (int j = 0; j < 4; ++j) {
    int e = es0 + j * 8;
    wbuf[(size_t)(e0 + e) * 32 + u] = w[j] * 0.08838834764831845f;
  }
}

// ------------------- k_agg: per-node gather reduction (1 wave per node)
__global__ __launch_bounds__(64) void k_agg(
    const float* __restrict__ wbuf, const float* __restrict__ Y,
    const int* __restrict__ start, const int* __restrict__ order,
    float* __restrict__ agg)
{
  const int n = blockIdx.x;
  const int t = threadIdx.x;
  const int c = t & 31;
  const int dh = t >> 5;
  const int s0 = start[n], s1 = start[n + 1];
  float a0 = 0.f, a1 = 0.f;
  for (int i = s0; i < s1; ++i) {
    int e = order[i];
    float wv = wbuf[(size_t)e * 32 + c];
    float y0 = Y[e * 4 + dh * 2 + 0];
    float y1 = Y[e * 4 + dh * 2 + 1];
    a0 += wv * y0;
    a1 += wv * y1;
  }
  float* ap = agg + (size_t)n * 128 + c * 4 + dh * 2;
  ap[0] = a0;
  ap[1] = a1;
}

// --------- k2: gather agg, tensor-product mix -> scalars (E,64) and V_out
__global__ __launch_bounds__(256) void k2_mix(
    const float* __restrict__ V, const int* __restrict__ esrc,
    const float* __restrict__ Wlin, const float* __restrict__ agg,
    float* __restrict__ scal, float* __restrict__ vout)
{
  __shared__ __align__(16) float Wls[64 * 32];
  __shared__ __align__(16) float Vv[8][64][4];
  __shared__ int srcs[8];
  const int t = threadIdx.x;
  const int e0 = blockIdx.x * 8;
  for (int i = t; i < 512; i += 256)
    *(float4*)&Wls[i * 4] = *(const float4*)&Wlin[i * 4];
  if (t < 8) srcs[t] = esrc[e0 + t];
  __syncthreads();

  const int sub = t >> 5, u = t & 31;
  const int e = e0 + sub;
  float4 a = *(const float4*)&agg[(size_t)srcs[sub] * 128 + u * 4];
  a.x *= 0.25f; a.y *= 0.25f; a.z *= 0.25f; a.w *= 0.25f;
  float4 b = *(const float4*)&V[(size_t)e * 128 + u * 4];
  float s1 = a.x * b.x;
  float s2 = (a.y * b.y + a.z * b.z + a.w * b.w) * 0.5773502691896258f;
  ((float2*)scal)[(size_t)e * 32 + u] = make_float2(s1, s2);
  Vv[sub][2 * u][0] = a.x * b.y;
  Vv[sub][2 * u][1] = a.x * b.z;
  Vv[sub][2 * u][2] = a.x * b.w;
  Vv[sub][2 * u + 1][0] = a.y * b.x;
  Vv[sub][2 * u + 1][1] = a.z * b.x;
  Vv[sub][2 * u + 1][2] = a.w * b.x;
  __syncthreads();

  float acc0 = 0.f, acc1 = 0.f, acc2 = 0.f;
  #pragma unroll 8
  for (int up = 0; up < 64; ++up) {
    float wl = Wls[up * 32 + u];
    float4 vv = *(const float4*)&Vv[sub][up][0];
    acc0 += vv.x * wl; acc1 += vv.y * wl; acc2 += vv.z * wl;
  }
  float* vp = vout + (size_t)e * 96 + u * 3;
  vp[0] = acc0 * 0.125f;
  vp[1] = acc1 * 0.125f;
  vp[2] = acc2 * 0.125f;
}

// -------- split-bf16 MFMA GEMM: C = A@B*scale, A f32 (E x K), B f32 (K x 128)
// A,B split to hi/lo bf16 in-kernel; 3-product accumulation ~ f32 accurate.
template <int K, bool SILU, bool CONCAT, bool ENV>
__global__ __launch_bounds__(256) void gemm_mfma(
    const float* __restrict__ A0, const float* __restrict__ A1,
    const float* __restrict__ B, const float* __restrict__ rvec,
    float* __restrict__ C, float scale)
{
  // rows padded to 40 elems (80 B) -> 20-bank stride, ~2-way max (free)
  __shared__ __align__(16) unsigned short Ah[128][40];
  __shared__ __align__(16) unsigned short Al[128][40];
  __shared__ __align__(16) unsigned short Bh[128][40];  // [n][k] transposed
  __shared__ __align__(16) unsigned short Bl[128][40];

  const int t = threadIdx.x;
  const int e0 = blockIdx.x * 128;
  const int lane = t & 63;
  const int w = t >> 6;
  const int wr = w >> 1, wc = w & 1;        // 2x2 wave grid, 64x64 per wave
  const int l15 = lane & 15, l4 = lane >> 4;

  f32x4 acc[4][4];
  #pragma unroll
  for (int i = 0; i < 4; ++i)
    #pragma unroll
    for (int j = 0; j < 4; ++j) acc[i][j] = (f32x4)(0.f);

  const int arow = t >> 1, ac0 = (t & 1) * 16;   // A: 16 f32 per thread
  const int bn = t & 127, bkh = (t >> 7) * 16;   // B: col bn, 16 k-rows

  for (int kc = 0; kc < K; kc += 32) {
    // ---- load A chunk (128 x 32 f32) to regs
    float av[16];
    const float* ap;
    if (!CONCAT || kc < 128)
      ap = A0 + (size_t)(e0 + arow) * (CONCAT ? 128 : K) + kc + ac0;
    else
      ap = A1 + (size_t)(e0 + arow) * 64 + (kc - 128) + ac0;
    #pragma unroll
    for (int i = 0; i < 4; ++i)
      *(float4*)&av[i * 4] = *(const float4*)(ap + i * 4);
    // ---- load B chunk (32 x 128 f32) column-wise (coalesced along n)
    float bv[16];
    #pragma unroll
    for (int j = 0; j < 16; ++j)
      bv[j] = B[(size_t)(kc + bkh + j) * 128 + bn] * scale;

    __syncthreads();  // previous chunk fully consumed

    // ---- split & write LDS
    #pragma unroll
    for (int half = 0; half < 2; ++half) {
      short8 ph, pl;
      #pragma unroll
      for (int j = 0; j < 8; ++j) {
        float v = av[half * 8 + j];
        unsigned short h = f2bf(v);
        ph[j] = (short)h;
        pl[j] = (short)f2bf(v - bf2f(h));
      }
      *(short8*)&Ah[arow][ac0 + half * 8] = ph;
      *(short8*)&Al[arow][ac0 + half * 8] = pl;
    }
    #pragma unroll
    for (int half = 0; half < 2; ++half) {
      short8 ph, pl;
      #pragma unroll
      for (int j = 0; j < 8; ++j) {
        float v = bv[half * 8 + j];
        unsigned short h = f2bf(v);
        ph[j] = (short)h;
        pl[j] = (short)f2bf(v - bf2f(h));
      }
      *(short8*)&Bh[bn][bkh + half * 8] = ph;
      *(short8*)&Bl[bn][bkh + half * 8] = pl;
    }

    __syncthreads();  // chunk staged

    // ---- fragments + MFMA (48 per wave per chunk)
    short8 bhf[4], blf[4];
    #pragma unroll
    for (int nf = 0; nf < 4; ++nf) {
      int rr = wc * 64 + nf * 16 + l15;
      bhf[nf] = *(short8*)&Bh[rr][l4 * 8];
      blf[nf] = *(short8*)&Bl[rr][l4 * 8];
    }
    #pragma unroll
    for (int mf = 0; mf < 4; ++mf) {
      int ar = wr * 64 + mf * 16 + l15;
      short8 ah = *(short8*)&Ah[ar][l4 * 8];
      short8 al = *(short8*)&Al[ar][l4 * 8];
      #pragma unroll
      for (int nf = 0; nf < 4; ++nf) {
        acc[mf][nf] = __builtin_amdgcn_mfma_f32_16x16x32_bf16(ah, bhf[nf], acc[mf][nf], 0, 0, 0);
        acc[mf][nf] = __builtin_amdgcn_mfma_f32_16x16x32_bf16(ah, blf[nf], acc[mf][nf], 0, 0, 0);
        acc[mf][nf] = __builtin_amdgcn_mfma_f32_16x16x32_bf16(al, bhf[nf], acc[mf][nf], 0, 0, 0);
      }
    }
  }

  // ---- epilogue: C/D layout col=lane&15, row=(lane>>4)*4+reg
  #pragma unroll
  for (int mf = 0; mf < 4; ++mf) {
    float env4[4];
    if (ENV) {
      #pragma unroll
      for (int rr = 0; rr < 4; ++rr) {
        int row = e0 + wr * 64 + mf * 16 + l4 * 4 + rr;
        float rx = rvec[row * 3 + 0];
        float ry = rvec[row * 3 + 1];
        float rz = rvec[row * 3 + 2];
        float d2 = rx * rx + ry * ry + rz * rz;
        float d = (d2 == 0.f) ? 1.f : sqrtf(d2);
        float d3 = d * d * d;
        env4[rr] = (d < 1.f) ? (1.f + d3 * d3 * (-28.f + d * (48.f - 21.f * d))) : 0.f;
      }
    }
    #pragma unroll
    for (int nf = 0; nf < 4; ++nf) {
      #pragma unroll
      for (int rr = 0; rr < 4; ++rr) {
        float z = acc[mf][nf][rr];
        if (SILU) z = z / (1.f + __expf(-z));
        if (ENV) z *= env4[rr];
        int row = e0 + wr * 64 + mf * 16 + l4 * 4 + rr;
        C[(size_t)row * 128 + wc * 64 + nf * 16 + l15] = z;
      }
    }
  }
}

extern "C" void kernel_launch(void* const* d_in, const int* in_sizes, int n_in,
                              void* d_out, int out_size, void* d_ws, size_t ws_size,
                              hipStream_t stream)
{
  const float* x    = (const float*)d_in[0];
  const float* V    = (const float*)d_in[1];
  const float* r    = (const float*)d_in[2];
  const float* Y    = (const float*)d_in[3];
  const int*   es   = (const int*)d_in[4];
  const float* W1   = (const float*)d_in[5];
  const float* W2a  = (const float*)d_in[6];
  const float* W2b  = (const float*)d_in[7];
  const float* W2c  = (const float*)d_in[8];
  const float* Wlin = (const float*)d_in[9];

  float* ws   = (float*)d_ws;
  float* agg  = ws;                          // [0, 3.2M)
  float* wbuf = ws + 3200000;                // [3.2M, 16M) — dead after k_agg
  float* scal = ws + 3200000;                // [3.2M, 28.8M) — overlays wbuf
  int*   ci   = (int*)(ws + 28800000);
  int*   cnt    = ci;
  int*   startv = ci + 25000;
  int*   cursor = ci + 50008;
  int*   order  = ci + 75008;
  float* h2   = ws;                          // [0, 51.2M) — after scal dead
  float* xout = (float*)d_out;
  float* vout = (float*)d_out + 51200000;
  float* h1   = xout;                        // staged in x_out region

  (void)in_sizes; (void)n_in; (void)out_size; (void)ws_size;

  hipMemsetAsync(cnt, 0, NNODES * sizeof(int), stream);
  khist<<<dim3((NE + 255) / 256), 256, 0, stream>>>(es, cnt);
  kscan<<<dim3(1), 1024, 0, stream>>>(cnt, startv, cursor);
  kfill<<<dim3((NE + 255) / 256), 256, 0, stream>>>(es, cursor, order);
  k1w<<<dim3(NE / 32), 256, 0, stream>>>(x, W1, wbuf);
  k_agg<<<dim3(NNODES), 64, 0, stream>>>(wbuf, Y, startv, order, agg);
  k2_mix<<<dim3(NE / 8), 256, 0, stream>>>(V, es, Wlin, agg, scal, vout);
  // h1 = silu(concat(x, scal) @ W2a / sqrt(192))
  gemm_mfma<192, true,  true,  false><<<dim3(NE / 128), 256, 0, stream>>>(
      x, scal, W2a, nullptr, h1, 0.07216878364870323f);
  // h2 = silu(h1 @ W2b / sqrt(128))
  gemm_mfma<128, true,  false, false><<<dim3(NE / 128), 256, 0, stream>>>(
      h1, nullptr, W2b, nullptr, h2, 0.08838834764831845f);
  // x_out = env(d) * (h2 @ W2c / sqrt(128))
  gemm_mfma<128, false, false, true ><<<dim3(NE / 128), 256, 0, stream>>>(
      h2, nullptr, W2c, r, xout, 0.08838834764831845f);
}

// Round 4
// 665.620 us; speedup vs baseline: 2.3707x; 1.1747x over previous
//
#include <hip/hip_runtime.h>

#define NE 400000
#define NNODES 25000

typedef __attribute__((ext_vector_type(8))) short short8;
typedef __attribute__((ext_vector_type(4))) float f32x4;

__device__ __forceinline__ unsigned short f2bf(float f) {
  unsigned int u = __float_as_uint(f);
  unsigned int r = u + 0x7fffu + ((u >> 16) & 1u);
  return (unsigned short)(r >> 16);
}
__device__ __forceinline__ float bf2f(unsigned short h) {
  return __uint_as_float(((unsigned int)h) << 16);
}

// ---------------------------------------------------- CSR build: histogram
__global__ __launch_bounds__(256) void khist(const int* __restrict__ esrc,
                                             int* __restrict__ cnt) {
  int e = blockIdx.x * 256 + threadIdx.x;
  if (e < NE) atomicAdd(&cnt[esrc[e]], 1);
}

// ------------------------------------- CSR build: exclusive scan (1 block)
__global__ __launch_bounds__(1024) void kscan(const int* __restrict__ cnt,
                                              int* __restrict__ start,
                                              int* __restrict__ cursor) {
  __shared__ int wsum[16];
  __shared__ int carry_s;
  const int t = threadIdx.x;
  const int lane = t & 63, wid = t >> 6;
  if (t == 0) carry_s = 0;
  __syncthreads();
  for (int base = 0; base < NNODES; base += 1024) {
    int idx = base + t;
    int v = (idx < NNODES) ? cnt[idx] : 0;
    int incl = v;
    #pragma unroll
    for (int off = 1; off < 64; off <<= 1) {
      int u = __shfl_up(incl, off, 64);
      if (lane >= off) incl += u;
    }
    if (lane == 63) wsum[wid] = incl;
    __syncthreads();
    if (wid == 0) {
      int wv = (lane < 16) ? wsum[lane] : 0;
      int wincl = wv;
      #pragma unroll
      for (int off = 1; off < 16; off <<= 1) {
        int u = __shfl_up(wincl, off, 64);
        if (lane >= off) wincl += u;
      }
      if (lane < 16) wsum[lane] = wincl - wv;
    }
    __syncthreads();
    int excl = incl - v + wsum[wid] + carry_s;
    if (idx < NNODES) { start[idx] = excl; cursor[idx] = excl; }
    __syncthreads();
    if (t == 1023) carry_s = excl + v;
    __syncthreads();
  }
  if (t == 0) start[NNODES] = carry_s;
}

// ---------------------------------------------------- CSR build: fill order
__global__ __launch_bounds__(256) void kfill(const int* __restrict__ esrc,
                                             int* __restrict__ cursor,
                                             int* __restrict__ order) {
  int e = blockIdx.x * 256 + threadIdx.x;
  if (e < NE) {
    int p = atomicAdd(&cursor[esrc[e]], 1);
    order[p] = e;
  }
}

// ----------------------------- k1w: w = x@W1/sqrt(128) -> wbuf (no atomics)
__global__ __launch_bounds__(256) void k1w(
    const float* __restrict__ x, const float* __restrict__ W1,
    float* __restrict__ wbuf)
{
  __shared__ __align__(16) float W1s[128 * 32];
  __shared__ __align__(16) float xs[32][128];
  const int t = threadIdx.x;
  const int e0 = blockIdx.x * 32;

  for (int i = t; i < 1024; i += 256)
    *(float4*)&W1s[i * 4] = *(const float4*)&W1[i * 4];
  for (int i = t; i < 1024; i += 256) {
    int row = i >> 5, c = (i & 31) * 4;
    *(float4*)&xs[row][c] = *(const float4*)&x[(size_t)(e0 + row) * 128 + c];
  }
  __syncthreads();

  const int u = t & 31;
  const int es0 = t >> 5;
  float w[4] = {0.f, 0.f, 0.f, 0.f};
  #pragma unroll
  for (int k = 0; k < 128; k += 4) {
    float w0 = W1s[(k + 0) * 32 + u];
    float w1 = W1s[(k + 1) * 32 + u];
    float w2 = W1s[(k + 2) * 32 + u];
    float w3 = W1s[(k + 3) * 32 + u];
    #pragma unroll
    for (int j = 0; j < 4; ++j) {
      float4 xv = *(const float4*)&xs[es0 + j * 8][k];
      w[j] += xv.x * w0 + xv.y * w1 + xv.z * w2 + xv.w * w3;
    }
  }
  #pragma unroll
  for (int j = 0; j < 4; ++j) {
    int e = es0 + j * 8;
    wbuf[(size_t)(e0 + e) * 32 + u] = w[j] * 0.08838834764831845f;
  }
}

// ------------------- k_agg: per-node gather reduction (1 wave per node)
__global__ __launch_bounds__(64) void k_agg(
    const float* __restrict__ wbuf, const float* __restrict__ Y,
    const int* __restrict__ start, const int* __restrict__ order,
    float* __restrict__ agg)
{
  const int n = blockIdx.x;
  const int t = threadIdx.x;
  const int c = t & 31;
  const int dh = t >> 5;
  const int s0 = start[n], s1 = start[n + 1];
  float a0 = 0.f, a1 = 0.f;
  for (int i = s0; i < s1; ++i) {
    int e = order[i];
    float wv = wbuf[(size_t)e * 32 + c];
    float y0 = Y[e * 4 + dh * 2 + 0];
    float y1 = Y[e * 4 + dh * 2 + 1];
    a0 += wv * y0;
    a1 += wv * y1;
  }
  float* ap = agg + (size_t)n * 128 + c * 4 + dh * 2;
  ap[0] = a0;
  ap[1] = a1;
}

// --------- k2: LDS-free register-MFMA mix: scal (E,64) + V_out
// wave = 16 edges; lane (l15,l4) owns edge e0w+l15, channels kc*16+l4*4+{0..3}
__global__ __launch_bounds__(256) void k2_mix(
    const float* __restrict__ V, const int* __restrict__ esrc,
    const float* __restrict__ Wlin, const float* __restrict__ agg,
    float* __restrict__ scal, float* __restrict__ vout)
{
  const int t = threadIdx.x;
  const int w = t >> 6, lane = t & 63;
  const int l15 = lane & 15, l4 = lane >> 4;
  const int e = blockIdx.x * 64 + w * 16 + l15;
  const int src = esrc[e];

  // ---- Wlin fragments (B-operand), scale 1/8 folded; hi/lo bf16 split
  short8 Wh[2][2], Wl[2][2];
  #pragma unroll
  for (int kc = 0; kc < 2; ++kc)
    #pragma unroll
    for (int nt = 0; nt < 2; ++nt) {
      #pragma unroll
      for (int jj = 0; jj < 8; ++jj) {
        float v = Wlin[(size_t)(kc * 32 + l4 * 8 + jj) * 32 + nt * 16 + l15] * 0.125f;
        unsigned short h = f2bf(v);
        Wh[kc][nt][jj] = (short)h;
        Wl[kc][nt][jj] = (short)f2bf(v - bf2f(h));
      }
    }

  f32x4 acc[3][2];
  #pragma unroll
  for (int i = 0; i < 3; ++i)
    #pragma unroll
    for (int nt = 0; nt < 2; ++nt) acc[i][nt] = (f32x4)(0.f);

  #pragma unroll
  for (int kc = 0; kc < 2; ++kc) {
    const int fbase = kc * 64 + l4 * 16;  // float offset into 128-float row
    float4 av[4], bv[4];
    const float* ap = agg + (size_t)src * 128 + fbase;
    const float* bp = V + (size_t)e * 128 + fbase;
    #pragma unroll
    for (int j = 0; j < 4; ++j) {
      av[j] = *(const float4*)(ap + j * 4);
      bv[j] = *(const float4*)(bp + j * 4);
      av[j].x *= 0.25f; av[j].y *= 0.25f; av[j].z *= 0.25f; av[j].w *= 0.25f;
    }
    // ---- scalars s1,s2 (f32 exact)
    float so[8];
    #pragma unroll
    for (int ch = 0; ch < 4; ++ch) {
      so[2 * ch]     = av[ch].x * bv[ch].x;
      so[2 * ch + 1] = (av[ch].y * bv[ch].y + av[ch].z * bv[ch].z +
                        av[ch].w * bv[ch].w) * 0.5773502691896258f;
    }
    float* sp = scal + (size_t)e * 64 + kc * 32 + l4 * 8;
    *(float4*)sp = *(float4*)&so[0];
    *(float4*)(sp + 4) = *(float4*)&so[4];
    // ---- A fragments per i, 3-product MFMA
    #pragma unroll
    for (int i = 0; i < 3; ++i) {
      short8 ah, al;
      #pragma unroll
      for (int ch = 0; ch < 4; ++ch) {
        float bvi = (i == 0) ? bv[ch].y : (i == 1) ? bv[ch].z : bv[ch].w;
        float avi = (i == 0) ? av[ch].y : (i == 1) ? av[ch].z : av[ch].w;
        float p0 = av[ch].x * bvi;   // v1 = a_s * b_v
        float p1 = avi * bv[ch].x;   // v2 = a_v * b_s
        unsigned short h0 = f2bf(p0), h1 = f2bf(p1);
        ah[2 * ch] = (short)h0;
        ah[2 * ch + 1] = (short)h1;
        al[2 * ch] = (short)f2bf(p0 - bf2f(h0));
        al[2 * ch + 1] = (short)f2bf(p1 - bf2f(h1));
      }
      #pragma unroll
      for (int nt = 0; nt < 2; ++nt) {
        acc[i][nt] = __builtin_amdgcn_mfma_f32_16x16x32_bf16(ah, Wh[kc][nt], acc[i][nt], 0, 0, 0);
        acc[i][nt] = __builtin_amdgcn_mfma_f32_16x16x32_bf16(ah, Wl[kc][nt], acc[i][nt], 0, 0, 0);
        acc[i][nt] = __builtin_amdgcn_mfma_f32_16x16x32_bf16(al, Wh[kc][nt], acc[i][nt], 0, 0, 0);
      }
    }
  }

  // ---- epilogue: C col=l15 (v), row=l4*4+rr (edge); vout[e][v][i]
  const int ebase = blockIdx.x * 64 + w * 16 + l4 * 4;
  #pragma unroll
  for (int nt = 0; nt < 2; ++nt) {
    #pragma unroll
    for (int rr = 0; rr < 4; ++rr) {
      float* vp = vout + (size_t)(ebase + rr) * 96 + (nt * 16 + l15) * 3;
      vp[0] = acc[0][nt][rr];
      vp[1] = acc[1][nt][rr];
      vp[2] = acc[2][nt][rr];
    }
  }
}

// -------- split-bf16 MFMA GEMM: C = A@B*scale, A f32 (E x K), B f32 (K x 128)
template <int K, bool SILU, bool CONCAT, bool ENV>
__global__ __launch_bounds__(256) void gemm_mfma(
    const float* __restrict__ A0, const float* __restrict__ A1,
    const float* __restrict__ B, const float* __restrict__ rvec,
    float* __restrict__ C, float scale)
{
  __shared__ __align__(16) unsigned short Ah[128][40];
  __shared__ __align__(16) unsigned short Al[128][40];
  __shared__ __align__(16) unsigned short Bh[128][40];  // [n][k] transposed
  __shared__ __align__(16) unsigned short Bl[128][40];

  const int t = threadIdx.x;
  const int e0 = blockIdx.x * 128;
  const int lane = t & 63;
  const int w = t >> 6;
  const int wr = w >> 1, wc = w & 1;
  const int l15 = lane & 15, l4 = lane >> 4;

  f32x4 acc[4][4];
  #pragma unroll
  for (int i = 0; i < 4; ++i)
    #pragma unroll
    for (int j = 0; j < 4; ++j) acc[i][j] = (f32x4)(0.f);

  const int arow = t >> 1, ac0 = (t & 1) * 16;
  const int bn = t & 127, bkh = (t >> 7) * 16;

  for (int kc = 0; kc < K; kc += 32) {
    float av[16];
    const float* ap;
    if (!CONCAT || kc < 128)
      ap = A0 + (size_t)(e0 + arow) * (CONCAT ? 128 : K) + kc + ac0;
    else
      ap = A1 + (size_t)(e0 + arow) * 64 + (kc - 128) + ac0;
    #pragma unroll
    for (int i = 0; i < 4; ++i)
      *(float4*)&av[i * 4] = *(const float4*)(ap + i * 4);
    float bv[16];
    #pragma unroll
    for (int j = 0; j < 16; ++j)
      bv[j] = B[(size_t)(kc + bkh + j) * 128 + bn] * scale;

    __syncthreads();

    #pragma unroll
    for (int half = 0; half < 2; ++half) {
      short8 ph, pl;
      #pragma unroll
      for (int j = 0; j < 8; ++j) {
        float v = av[half * 8 + j];
        unsigned short h = f2bf(v);
        ph[j] = (short)h;
        pl[j] = (short)f2bf(v - bf2f(h));
      }
      *(short8*)&Ah[arow][ac0 + half * 8] = ph;
      *(short8*)&Al[arow][ac0 + half * 8] = pl;
    }
    #pragma unroll
    for (int half = 0; half < 2; ++half) {
      short8 ph, pl;
      #pragma unroll
      for (int j = 0; j < 8; ++j) {
        float v = bv[half * 8 + j];
        unsigned short h = f2bf(v);
        ph[j] = (short)h;
        pl[j] = (short)f2bf(v - bf2f(h));
      }
      *(short8*)&Bh[bn][bkh + half * 8] = ph;
      *(short8*)&Bl[bn][bkh + half * 8] = pl;
    }

    __syncthreads();

    short8 bhf[4], blf[4];
    #pragma unroll
    for (int nf = 0; nf < 4; ++nf) {
      int rr = wc * 64 + nf * 16 + l15;
      bhf[nf] = *(short8*)&Bh[rr][l4 * 8];
      blf[nf] = *(short8*)&Bl[rr][l4 * 8];
    }
    #pragma unroll
    for (int mf = 0; mf < 4; ++mf) {
      int ar = wr * 64 + mf * 16 + l15;
      short8 ah = *(short8*)&Ah[ar][l4 * 8];
      short8 al = *(short8*)&Al[ar][l4 * 8];
      #pragma unroll
      for (int nf = 0; nf < 4; ++nf) {
        acc[mf][nf] = __builtin_amdgcn_mfma_f32_16x16x32_bf16(ah, bhf[nf], acc[mf][nf], 0, 0, 0);
        acc[mf][nf] = __builtin_amdgcn_mfma_f32_16x16x32_bf16(ah, blf[nf], acc[mf][nf], 0, 0, 0);
        acc[mf][nf] = __builtin_amdgcn_mfma_f32_16x16x32_bf16(al, bhf[nf], acc[mf][nf], 0, 0, 0);
      }
    }
  }

  #pragma unroll
  for (int mf = 0; mf < 4; ++mf) {
    float env4[4];
    if (ENV) {
      #pragma unroll
      for (int rr = 0; rr < 4; ++rr) {
        int row = e0 + wr * 64 + mf * 16 + l4 * 4 + rr;
        float rx = rvec[row * 3 + 0];
        float ry = rvec[row * 3 + 1];
        float rz = rvec[row * 3 + 2];
        float d2 = rx * rx + ry * ry + rz * rz;
        float d = (d2 == 0.f) ? 1.f : sqrtf(d2);
        float d3 = d * d * d;
        env4[rr] = (d < 1.f) ? (1.f + d3 * d3 * (-28.f + d * (48.f - 21.f * d))) : 0.f;
      }
    }
    #pragma unroll
    for (int nf = 0; nf < 4; ++nf) {
      #pragma unroll
      for (int rr = 0; rr < 4; ++rr) {
        float z = acc[mf][nf][rr];
        if (SILU) z = z / (1.f + __expf(-z));
        if (ENV) z *= env4[rr];
        int row = e0 + wr * 64 + mf * 16 + l4 * 4 + rr;
        C[(size_t)row * 128 + wc * 64 + nf * 16 + l15] = z;
      }
    }
  }
}

extern "C" void kernel_launch(void* const* d_in, const int* in_sizes, int n_in,
                              void* d_out, int out_size, void* d_ws, size_t ws_size,
                              hipStream_t stream)
{
  const float* x    = (const float*)d_in[0];
  const float* V    = (const float*)d_in[1];
  const float* r    = (const float*)d_in[2];
  const float* Y    = (const float*)d_in[3];
  const int*   es   = (const int*)d_in[4];
  const float* W1   = (const float*)d_in[5];
  const float* W2a  = (const float*)d_in[6];
  const float* W2b  = (const float*)d_in[7];
  const float* W2c  = (const float*)d_in[8];
  const float* Wlin = (const float*)d_in[9];

  float* ws   = (float*)d_ws;
  float* agg  = ws;                          // [0, 3.2M)
  float* wbuf = ws + 3200000;                // [3.2M, 16M) — dead after k_agg
  float* scal = ws + 3200000;                // [3.2M, 28.8M) — overlays wbuf
  int*   ci   = (int*)(ws + 28800000);
  int*   cnt    = ci;
  int*   startv = ci + 25000;
  int*   cursor = ci + 50008;
  int*   order  = ci + 75008;
  float* h2   = ws;                          // [0, 51.2M)
  float* xout = (float*)d_out;
  float* vout = (float*)d_out + 51200000;
  float* h1   = xout;

  (void)in_sizes; (void)n_in; (void)out_size; (void)ws_size;

  hipMemsetAsync(cnt, 0, NNODES * sizeof(int), stream);
  khist<<<dim3((NE + 255) / 256), 256, 0, stream>>>(es, cnt);
  kscan<<<dim3(1), 1024, 0, stream>>>(cnt, startv, cursor);
  kfill<<<dim3((NE + 255) / 256), 256, 0, stream>>>(es, cursor, order);
  k1w<<<dim3(NE / 32), 256, 0, stream>>>(x, W1, wbuf);
  k_agg<<<dim3(NNODES), 64, 0, stream>>>(wbuf, Y, startv, order, agg);
  k2_mix<<<dim3(NE / 64), 256, 0, stream>>>(V, es, Wlin, agg, scal, vout);
  gemm_mfma<192, true,  true,  false><<<dim3(NE / 128), 256, 0, stream>>>(
      x, scal, W2a, nullptr, h1, 0.07216878364870323f);
  gemm_mfma<128, true,  false, false><<<dim3(NE / 128), 256, 0, stream>>>(
      h1, nullptr, W2b, nullptr, h2, 0.08838834764831845f);
  gemm_mfma<128, false, false, true ><<<dim3(NE / 128), 256, 0, stream>>>(
      h2, nullptr, W2c, r, xout, 0.08838834764831845f);
}

// Round 5
// 586.388 us; speedup vs baseline: 2.6910x; 1.1351x over previous
//
#include <hip/hip_runtime.h>

#define NE 400000
#define NNODES 25000
#define SCAL_PITCH 68   // u32 elems per row (packed hi|lo), 34816 B total
#define B_PITCH 36      // u32 elems per row (packed hi|lo), 18432 B total
#define HS_PITCH 136    // bf16 elems per row (aliases scal region)

typedef __attribute__((ext_vector_type(8))) short short8;
typedef __attribute__((ext_vector_type(4))) float f32x4;

__device__ __forceinline__ unsigned short f2bf(float f) {
  unsigned int u = __float_as_uint(f);
  unsigned int r = u + 0x7fffu + ((u >> 16) & 1u);
  return (unsigned short)(r >> 16);
}
__device__ __forceinline__ float bf2f(unsigned short h) {
  return __uint_as_float(((unsigned int)h) << 16);
}
__device__ __forceinline__ unsigned int packhl(float v) {
  unsigned short h = f2bf(v);
  unsigned short l = f2bf(v - bf2f(h));
  return (unsigned int)h | ((unsigned int)l << 16);
}
union U8 { unsigned int u[4]; short8 s; };
__device__ __forceinline__ void unpack8(const uint4 q0, const uint4 q1,
                                        short8& h, short8& l) {
  U8 hu, lu;
  hu.u[0] = (q0.x & 0xFFFFu) | (q0.y << 16);
  hu.u[1] = (q0.z & 0xFFFFu) | (q0.w << 16);
  hu.u[2] = (q1.x & 0xFFFFu) | (q1.y << 16);
  hu.u[3] = (q1.z & 0xFFFFu) | (q1.w << 16);
  lu.u[0] = (q0.x >> 16) | (q0.y & 0xFFFF0000u);
  lu.u[1] = (q0.z >> 16) | (q0.w & 0xFFFF0000u);
  lu.u[2] = (q1.x >> 16) | (q1.y & 0xFFFF0000u);
  lu.u[3] = (q1.z >> 16) | (q1.w & 0xFFFF0000u);
  h = hu.s; l = lu.s;
}
__device__ __forceinline__ void split8(const float* a, short8& h, short8& l) {
  #pragma unroll
  for (int j = 0; j < 8; ++j) {
    unsigned short hh = f2bf(a[j]);
    h[j] = (short)hh;
    l[j] = (short)f2bf(a[j] - bf2f(hh));
  }
}

// ---------------------------------------------------- CSR build: histogram
__global__ __launch_bounds__(256) void khist(const int* __restrict__ esrc,
                                             int* __restrict__ cnt) {
  int e = blockIdx.x * 256 + threadIdx.x;
  if (e < NE) atomicAdd(&cnt[esrc[e]], 1);
}

// ------------------------------------- CSR build: exclusive scan (1 block)
__global__ __launch_bounds__(1024) void kscan(const int* __restrict__ cnt,
                                              int* __restrict__ start,
                                              int* __restrict__ cursor) {
  __shared__ int wsum[16];
  __shared__ int carry_s;
  const int t = threadIdx.x;
  const int lane = t & 63, wid = t >> 6;
  if (t == 0) carry_s = 0;
  __syncthreads();
  for (int base = 0; base < NNODES; base += 1024) {
    int idx = base + t;
    int v = (idx < NNODES) ? cnt[idx] : 0;
    int incl = v;
    #pragma unroll
    for (int off = 1; off < 64; off <<= 1) {
      int u = __shfl_up(incl, off, 64);
      if (lane >= off) incl += u;
    }
    if (lane == 63) wsum[wid] = incl;
    __syncthreads();
    if (wid == 0) {
      int wv = (lane < 16) ? wsum[lane] : 0;
      int wincl = wv;
      #pragma unroll
      for (int off = 1; off < 16; off <<= 1) {
        int u = __shfl_up(wincl, off, 64);
        if (lane >= off) wincl += u;
      }
      if (lane < 16) wsum[lane] = wincl - wv;
    }
    __syncthreads();
    int excl = incl - v + wsum[wid] + carry_s;
    if (idx < NNODES) { start[idx] = excl; cursor[idx] = excl; }
    __syncthreads();
    if (t == 1023) carry_s = excl + v;
    __syncthreads();
  }
  if (t == 0) start[NNODES] = carry_s;
}

// ---------------------------------------------------- CSR build: fill order
__global__ __launch_bounds__(256) void kfill(const int* __restrict__ esrc,
                                             int* __restrict__ cursor,
                                             int* __restrict__ order) {
  int e = blockIdx.x * 256 + threadIdx.x;
  if (e < NE) {
    int p = atomicAdd(&cursor[esrc[e]], 1);
    order[p] = e;
  }
}

// ----------------------------- k1w: w = x@W1/sqrt(128) -> wbuf (no atomics)
__global__ __launch_bounds__(256) void k1w(
    const float* __restrict__ x, const float* __restrict__ W1,
    float* __restrict__ wbuf)
{
  __shared__ __align__(16) float W1s[128 * 32];
  __shared__ __align__(16) float xs[32][128];
  const int t = threadIdx.x;
  const int e0 = blockIdx.x * 32;

  for (int i = t; i < 1024; i += 256)
    *(float4*)&W1s[i * 4] = *(const float4*)&W1[i * 4];
  for (int i = t; i < 1024; i += 256) {
    int row = i >> 5, c = (i & 31) * 4;
    *(float4*)&xs[row][c] = *(const float4*)&x[(size_t)(e0 + row) * 128 + c];
  }
  __syncthreads();

  const int u = t & 31;
  const int es0 = t >> 5;
  float w[4] = {0.f, 0.f, 0.f, 0.f};
  #pragma unroll
  for (int k = 0; k < 128; k += 4) {
    float w0 = W1s[(k + 0) * 32 + u];
    float w1 = W1s[(k + 1) * 32 + u];
    float w2 = W1s[(k + 2) * 32 + u];
    float w3 = W1s[(k + 3) * 32 + u];
    #pragma unroll
    for (int j = 0; j < 4; ++j) {
      float4 xv = *(const float4*)&xs[es0 + j * 8][k];
      w[j] += xv.x * w0 + xv.y * w1 + xv.z * w2 + xv.w * w3;
    }
  }
  #pragma unroll
  for (int j = 0; j < 4; ++j) {
    int e = es0 + j * 8;
    wbuf[(size_t)(e0 + e) * 32 + u] = w[j] * 0.08838834764831845f;
  }
}

// ------------------- k_agg: per-node gather reduction (1 wave per node)
__global__ __launch_bounds__(64) void k_agg(
    const float* __restrict__ wbuf, const float* __restrict__ Y,
    const int* __restrict__ start, const int* __restrict__ order,
    float* __restrict__ agg)
{
  const int n = blockIdx.x;
  const int t = threadIdx.x;
  const int c = t & 31;
  const int dh = t >> 5;
  const int s0 = start[n], s1 = start[n + 1];
  float a0 = 0.f, a1 = 0.f;
  for (int i = s0; i < s1; ++i) {
    int e = order[i];
    float wv = wbuf[(size_t)e * 32 + c];
    float y0 = Y[e * 4 + dh * 2 + 0];
    float y1 = Y[e * 4 + dh * 2 + 1];
    a0 += wv * y0;
    a1 += wv * y1;
  }
  float* ap = agg + (size_t)n * 128 + c * 4 + dh * 2;
  ap[0] = a0;
  ap[1] = a1;
}

// =================== fused: mix + vout + 3-stage MLP + env ===================
__global__ __launch_bounds__(256) void kfused(
    const float* __restrict__ x, const float* __restrict__ V,
    const float* __restrict__ r, const int* __restrict__ esrc,
    const float* __restrict__ agg, const float* __restrict__ Wlin,
    const float* __restrict__ W2a, const float* __restrict__ W2b,
    const float* __restrict__ W2c,
    float* __restrict__ xout, float* __restrict__ vout)
{
  __shared__ __align__(16) unsigned int smem0[128 * SCAL_PITCH]; // scal packed -> Hs bf16
  __shared__ __align__(16) unsigned int smemB[128 * B_PITCH];    // W staging packed
  unsigned short* Hs = (unsigned short*)smem0;

  const int t = threadIdx.x;
  const int w = t >> 6, lane = t & 63;
  const int wr = w >> 1, wc = w & 1;
  const int l15 = lane & 15, l4 = lane >> 4;
  const int e0 = blockIdx.x * 128;

  // ---------------- phase A: tensor-product mix (scal -> LDS, vout -> global)
  {
    short8 WhF[2][2], WlF[2][2];
    #pragma unroll
    for (int kc2 = 0; kc2 < 2; ++kc2)
      #pragma unroll
      for (int nt = 0; nt < 2; ++nt) {
        float wf[8];
        #pragma unroll
        for (int jj = 0; jj < 8; ++jj)
          wf[jj] = Wlin[(size_t)(kc2 * 32 + l4 * 8 + jj) * 32 + nt * 16 + l15] * 0.125f;
        split8(wf, WhF[kc2][nt], WlF[kc2][nt]);
      }

    #pragma unroll
    for (int pass = 0; pass < 2; ++pass) {
      const int er = w * 32 + pass * 16 + l15;
      const int e = e0 + er;
      const int src = esrc[e];
      f32x4 accv[3][2];
      #pragma unroll
      for (int i = 0; i < 3; ++i)
        #pragma unroll
        for (int nt = 0; nt < 2; ++nt) accv[i][nt] = (f32x4)(0.f);

      #pragma unroll
      for (int kc2 = 0; kc2 < 2; ++kc2) {
        float4 av4[4], bv4[4];
        const float* ap = agg + (size_t)src * 128 + kc2 * 64 + l4 * 16;
        const float* bp = V + (size_t)e * 128 + kc2 * 64 + l4 * 16;
        #pragma unroll
        for (int j = 0; j < 4; ++j) {
          av4[j] = *(const float4*)(ap + j * 4);
          bv4[j] = *(const float4*)(bp + j * 4);
          av4[j].x *= 0.25f; av4[j].y *= 0.25f; av4[j].z *= 0.25f; av4[j].w *= 0.25f;
        }
        unsigned int sp[8];
        #pragma unroll
        for (int ch = 0; ch < 4; ++ch) {
          float s1 = av4[ch].x * bv4[ch].x;
          float s2 = (av4[ch].y * bv4[ch].y + av4[ch].z * bv4[ch].z +
                      av4[ch].w * bv4[ch].w) * 0.5773502691896258f;
          sp[2 * ch] = packhl(s1);
          sp[2 * ch + 1] = packhl(s2);
        }
        *(uint4*)&smem0[er * SCAL_PITCH + kc2 * 32 + l4 * 8] = *(uint4*)&sp[0];
        *(uint4*)&smem0[er * SCAL_PITCH + kc2 * 32 + l4 * 8 + 4] = *(uint4*)&sp[4];

        #pragma unroll
        for (int i = 0; i < 3; ++i) {
          short8 ah, al;
          #pragma unroll
          for (int ch = 0; ch < 4; ++ch) {
            float bvi = (i == 0) ? bv4[ch].y : (i == 1) ? bv4[ch].z : bv4[ch].w;
            float avi = (i == 0) ? av4[ch].y : (i == 1) ? av4[ch].z : av4[ch].w;
            float p0 = av4[ch].x * bvi;
            float p1 = avi * bv4[ch].x;
            unsigned short h0 = f2bf(p0), h1 = f2bf(p1);
            ah[2 * ch] = (short)h0;
            ah[2 * ch + 1] = (short)h1;
            al[2 * ch] = (short)f2bf(p0 - bf2f(h0));
            al[2 * ch + 1] = (short)f2bf(p1 - bf2f(h1));
          }
          #pragma unroll
          for (int nt = 0; nt < 2; ++nt) {
            accv[i][nt] = __builtin_amdgcn_mfma_f32_16x16x32_bf16(ah, WhF[kc2][nt], accv[i][nt], 0, 0, 0);
            accv[i][nt] = __builtin_amdgcn_mfma_f32_16x16x32_bf16(ah, WlF[kc2][nt], accv[i][nt], 0, 0, 0);
            accv[i][nt] = __builtin_amdgcn_mfma_f32_16x16x32_bf16(al, WhF[kc2][nt], accv[i][nt], 0, 0, 0);
          }
        }
      }
      const int ebase = e0 + w * 32 + pass * 16 + l4 * 4;
      #pragma unroll
      for (int nt = 0; nt < 2; ++nt)
        #pragma unroll
        for (int rr = 0; rr < 4; ++rr) {
          float* vp = vout + (size_t)(ebase + rr) * 96 + (nt * 16 + l15) * 3;
          vp[0] = accv[0][nt][rr];
          vp[1] = accv[1][nt][rr];
          vp[2] = accv[2][nt][rr];
        }
    }
  }

  f32x4 acc[4][4];

  // ---------------- stage 1: h1 = silu(concat(x, scal) @ W2a / sqrt(192))
  #pragma unroll
  for (int i = 0; i < 4; ++i)
    #pragma unroll
    for (int j = 0; j < 4; ++j) acc[i][j] = (f32x4)(0.f);

  for (int kc = 0; kc < 192; kc += 32) {
    // stage W2a chunk (packed hi|lo)
    {
      const int bn = t & 127, bkh = (t >> 7) * 16;
      unsigned int bpk[16];
      #pragma unroll
      for (int j = 0; j < 16; ++j)
        bpk[j] = packhl(W2a[(size_t)(kc + bkh + j) * 128 + bn] * 0.07216878364870323f);
      __syncthreads();
      #pragma unroll
      for (int i = 0; i < 4; ++i)
        *(uint4*)&smemB[bn * B_PITCH + bkh + 4 * i] = *(uint4*)&bpk[4 * i];
      __syncthreads();
    }
    short8 bh[4], bl[4];
    #pragma unroll
    for (int nf = 0; nf < 4; ++nf) {
      int rB = wc * 64 + nf * 16 + l15;
      uint4 q0 = *(const uint4*)&smemB[rB * B_PITCH + l4 * 8];
      uint4 q1 = *(const uint4*)&smemB[rB * B_PITCH + l4 * 8 + 4];
      unpack8(q0, q1, bh[nf], bl[nf]);
    }
    if (kc < 128) {
      #pragma unroll
      for (int mf = 0; mf < 4; ++mf) {
        const float* xp = x + (size_t)(e0 + wr * 64 + mf * 16 + l15) * 128 + kc + l4 * 8;
        float a8[8];
        *(float4*)&a8[0] = *(const float4*)xp;
        *(float4*)&a8[4] = *(const float4*)(xp + 4);
        short8 ah, al;
        split8(a8, ah, al);
        #pragma unroll
        for (int nf = 0; nf < 4; ++nf) {
          acc[mf][nf] = __builtin_amdgcn_mfma_f32_16x16x32_bf16(ah, bh[nf], acc[mf][nf], 0, 0, 0);
          acc[mf][nf] = __builtin_amdgcn_mfma_f32_16x16x32_bf16(ah, bl[nf], acc[mf][nf], 0, 0, 0);
          acc[mf][nf] = __builtin_amdgcn_mfma_f32_16x16x32_bf16(al, bh[nf], acc[mf][nf], 0, 0, 0);
        }
      }
    } else {
      #pragma unroll
      for (int mf = 0; mf < 4; ++mf) {
        int ar = wr * 64 + mf * 16 + l15;
        uint4 q0 = *(const uint4*)&smem0[ar * SCAL_PITCH + (kc - 128) + l4 * 8];
        uint4 q1 = *(const uint4*)&smem0[ar * SCAL_PITCH + (kc - 128) + l4 * 8 + 4];
        short8 ah, al;
        unpack8(q0, q1, ah, al);
        #pragma unroll
        for (int nf = 0; nf < 4; ++nf) {
          acc[mf][nf] = __builtin_amdgcn_mfma_f32_16x16x32_bf16(ah, bh[nf], acc[mf][nf], 0, 0, 0);
          acc[mf][nf] = __builtin_amdgcn_mfma_f32_16x16x32_bf16(ah, bl[nf], acc[mf][nf], 0, 0, 0);
          acc[mf][nf] = __builtin_amdgcn_mfma_f32_16x16x32_bf16(al, bh[nf], acc[mf][nf], 0, 0, 0);
        }
      }
    }
  }

  // h1 -> Hs (bf16), silu applied
  __syncthreads();
  #pragma unroll
  for (int mf = 0; mf < 4; ++mf)
    #pragma unroll
    for (int nf = 0; nf < 4; ++nf)
      #pragma unroll
      for (int rr = 0; rr < 4; ++rr) {
        float z = acc[mf][nf][rr];
        z = z / (1.f + __expf(-z));
        Hs[(wr * 64 + mf * 16 + l4 * 4 + rr) * HS_PITCH + wc * 64 + nf * 16 + l15] = f2bf(z);
      }

  // ---------------- stage 2: h2 = silu(h1 @ W2b / sqrt(128))
  #pragma unroll
  for (int i = 0; i < 4; ++i)
    #pragma unroll
    for (int j = 0; j < 4; ++j) acc[i][j] = (f32x4)(0.f);

  for (int kc = 0; kc < 128; kc += 32) {
    {
      const int bn = t & 127, bkh = (t >> 7) * 16;
      unsigned int bpk[16];
      #pragma unroll
      for (int j = 0; j < 16; ++j)
        bpk[j] = packhl(W2b[(size_t)(kc + bkh + j) * 128 + bn] * 0.08838834764831845f);
      __syncthreads();
      #pragma unroll
      for (int i = 0; i < 4; ++i)
        *(uint4*)&smemB[bn * B_PITCH + bkh + 4 * i] = *(uint4*)&bpk[4 * i];
      __syncthreads();
    }
    short8 bh[4], bl[4];
    #pragma unroll
    for (int nf = 0; nf < 4; ++nf) {
      int rB = wc * 64 + nf * 16 + l15;
      uint4 q0 = *(const uint4*)&smemB[rB * B_PITCH + l4 * 8];
      uint4 q1 = *(const uint4*)&smemB[rB * B_PITCH + l4 * 8 + 4];
      unpack8(q0, q1, bh[nf], bl[nf]);
    }
    #pragma unroll
    for (int mf = 0; mf < 4; ++mf) {
      short8 ah = *(const short8*)&Hs[(wr * 64 + mf * 16 + l15) * HS_PITCH + kc + l4 * 8];
      #pragma unroll
      for (int nf = 0; nf < 4; ++nf) {
        acc[mf][nf] = __builtin_amdgcn_mfma_f32_16x16x32_bf16(ah, bh[nf], acc[mf][nf], 0, 0, 0);
        acc[mf][nf] = __builtin_amdgcn_mfma_f32_16x16x32_bf16(ah, bl[nf], acc[mf][nf], 0, 0, 0);
      }
    }
  }

  // h2 -> Hs (bf16), silu applied
  __syncthreads();
  #pragma unroll
  for (int mf = 0; mf < 4; ++mf)
    #pragma unroll
    for (int nf = 0; nf < 4; ++nf)
      #pragma unroll
      for (int rr = 0; rr < 4; ++rr) {
        float z = acc[mf][nf][rr];
        z = z / (1.f + __expf(-z));
        Hs[(wr * 64 + mf * 16 + l4 * 4 + rr) * HS_PITCH + wc * 64 + nf * 16 + l15] = f2bf(z);
      }

  // ---------------- stage 3: x_out = env(d) * (h2 @ W2c / sqrt(128))
  #pragma unroll
  for (int i = 0; i < 4; ++i)
    #pragma unroll
    for (int j = 0; j < 4; ++j) acc[i][j] = (f32x4)(0.f);

  for (int kc = 0; kc < 128; kc += 32) {
    {
      const int bn = t & 127, bkh = (t >> 7) * 16;
      unsigned int bpk[16];
      #pragma unroll
      for (int j = 0; j < 16; ++j)
        bpk[j] = packhl(W2c[(size_t)(kc + bkh + j) * 128 + bn] * 0.08838834764831845f);
      __syncthreads();
      #pragma unroll
      for (int i = 0; i < 4; ++i)
        *(uint4*)&smemB[bn * B_PITCH + bkh + 4 * i] = *(uint4*)&bpk[4 * i];
      __syncthreads();
    }
    short8 bh[4], bl[4];
    #pragma unroll
    for (int nf = 0; nf < 4; ++nf) {
      int rB = wc * 64 + nf * 16 + l15;
      uint4 q0 = *(const uint4*)&smemB[rB * B_PITCH + l4 * 8];
      uint4 q1 = *(const uint4*)&smemB[rB * B_PITCH + l4 * 8 + 4];
      unpack8(q0, q1, bh[nf], bl[nf]);
    }
    #pragma unroll
    for (int mf = 0; mf < 4; ++mf) {
      short8 ah = *(const short8*)&Hs[(wr * 64 + mf * 16 + l15) * HS_PITCH + kc + l4 * 8];
      #pragma unroll
      for (int nf = 0; nf < 4; ++nf) {
        acc[mf][nf] = __builtin_amdgcn_mfma_f32_16x16x32_bf16(ah, bh[nf], acc[mf][nf], 0, 0, 0);
        acc[mf][nf] = __builtin_amdgcn_mfma_f32_16x16x32_bf16(ah, bl[nf], acc[mf][nf], 0, 0, 0);
      }
    }
  }

  #pragma unroll
  for (int mf = 0; mf < 4; ++mf) {
    float env4[4];
    #pragma unroll
    for (int rr = 0; rr < 4; ++rr) {
      int row = e0 + wr * 64 + mf * 16 + l4 * 4 + rr;
      float rx = r[row * 3 + 0];
      float ry = r[row * 3 + 1];
      float rz = r[row * 3 + 2];
      float d2 = rx * rx + ry * ry + rz * rz;
      float d = (d2 == 0.f) ? 1.f : sqrtf(d2);
      float d3 = d * d * d;
      env4[rr] = (d < 1.f) ? (1.f + d3 * d3 * (-28.f + d * (48.f - 21.f * d))) : 0.f;
    }
    #pragma unroll
    for (int nf = 0; nf < 4; ++nf)
      #pragma unroll
      for (int rr = 0; rr < 4; ++rr) {
        int row = e0 + wr * 64 + mf * 16 + l4 * 4 + rr;
        xout[(size_t)row * 128 + wc * 64 + nf * 16 + l15] = acc[mf][nf][rr] * env4[rr];
      }
  }
}

extern "C" void kernel_launch(void* const* d_in, const int* in_sizes, int n_in,
                              void* d_out, int out_size, void* d_ws, size_t ws_size,
                              hipStream_t stream)
{
  const float* x    = (const float*)d_in[0];
  const float* V    = (const float*)d_in[1];
  const float* r    = (const float*)d_in[2];
  const float* Y    = (const float*)d_in[3];
  const int*   es   = (const int*)d_in[4];
  const float* W1   = (const float*)d_in[5];
  const float* W2a  = (const float*)d_in[6];
  const float* W2b  = (const float*)d_in[7];
  const float* W2c  = (const float*)d_in[8];
  const float* Wlin = (const float*)d_in[9];

  float* ws   = (float*)d_ws;
  float* agg  = ws;                          // [0, 3.2M)
  float* wbuf = ws + 3200000;                // [3.2M, 16M)
  int*   ci   = (int*)(ws + 28800000);
  int*   cnt    = ci;
  int*   startv = ci + 25000;
  int*   cursor = ci + 50008;
  int*   order  = ci + 75008;
  float* xout = (float*)d_out;
  float* vout = (float*)d_out + 51200000;

  (void)in_sizes; (void)n_in; (void)out_size; (void)ws_size;

  hipMemsetAsync(cnt, 0, NNODES * sizeof(int), stream);
  khist<<<dim3((NE + 255) / 256), 256, 0, stream>>>(es, cnt);
  kscan<<<dim3(1), 1024, 0, stream>>>(cnt, startv, cursor);
  kfill<<<dim3((NE + 255) / 256), 256, 0, stream>>>(es, cursor, order);
  k1w<<<dim3(NE / 32), 256, 0, stream>>>(x, W1, wbuf);
  k_agg<<<dim3(NNODES), 64, 0, stream>>>(wbuf, Y, startv, order, agg);
  kfused<<<dim3(NE / 128), 256, 0, stream>>>(x, V, r, es, agg, Wlin,
                                             W2a, W2b, W2c, xout, vout);
}

// Round 6
// 529.845 us; speedup vs baseline: 2.9781x; 1.1067x over previous
//
#include <hip/hip_runtime.h>

#define NE 400000
#define NNODES 25000

typedef __attribute__((ext_vector_type(8))) short short8;
typedef __attribute__((ext_vector_type(4))) float f32x4;

// weight-plane ushort offsets inside wp
#define W2A_H 0
#define W2A_L 24576
#define W2B_H 49152
#define W2B_L 65536
#define W2C_H 81920
#define W2C_L 98304
#define WLIN_H 114688
#define WLIN_L 116736

__device__ __forceinline__ unsigned short f2bf(float f) {
  unsigned int u = __float_as_uint(f);
  unsigned int r = u + 0x7fffu + ((u >> 16) & 1u);
  return (unsigned short)(r >> 16);
}
__device__ __forceinline__ float bf2f(unsigned short h) {
  return __uint_as_float(((unsigned int)h) << 16);
}
__device__ __forceinline__ unsigned int packhl(float v) {
  unsigned short h = f2bf(v);
  unsigned short l = f2bf(v - bf2f(h));
  return (unsigned int)h | ((unsigned int)l << 16);
}
union U8 { unsigned int u[4]; short8 s; };
__device__ __forceinline__ void unpack8(const uint4 q0, const uint4 q1,
                                        short8& h, short8& l) {
  U8 hu, lu;
  hu.u[0] = (q0.x & 0xFFFFu) | (q0.y << 16);
  hu.u[1] = (q0.z & 0xFFFFu) | (q0.w << 16);
  hu.u[2] = (q1.x & 0xFFFFu) | (q1.y << 16);
  hu.u[3] = (q1.z & 0xFFFFu) | (q1.w << 16);
  lu.u[0] = (q0.x >> 16) | (q0.y & 0xFFFF0000u);
  lu.u[1] = (q0.z >> 16) | (q0.w & 0xFFFF0000u);
  lu.u[2] = (q1.x >> 16) | (q1.y & 0xFFFF0000u);
  lu.u[3] = (q1.z >> 16) | (q1.w & 0xFFFF0000u);
  h = hu.s; l = lu.s;
}
__device__ __forceinline__ void split8(const float* a, short8& h, short8& l) {
  #pragma unroll
  for (int j = 0; j < 8; ++j) {
    unsigned short hh = f2bf(a[j]);
    h[j] = (short)hh;
    l[j] = (short)f2bf(a[j] - bf2f(hh));
  }
}

// ---------------------------------------------------- CSR build: histogram
__global__ __launch_bounds__(256) void khist(const int* __restrict__ esrc,
                                             int* __restrict__ cnt) {
  int e = blockIdx.x * 256 + threadIdx.x;
  if (e < NE) atomicAdd(&cnt[esrc[e]], 1);
}

// ------------------------------------- CSR build: exclusive scan (1 block)
__global__ __launch_bounds__(1024) void kscan(const int* __restrict__ cnt,
                                              int* __restrict__ start,
                                              int* __restrict__ cursor) {
  __shared__ int wsum[16];
  __shared__ int carry_s;
  const int t = threadIdx.x;
  const int lane = t & 63, wid = t >> 6;
  if (t == 0) carry_s = 0;
  __syncthreads();
  for (int base = 0; base < NNODES; base += 1024) {
    int idx = base + t;
    int v = (idx < NNODES) ? cnt[idx] : 0;
    int incl = v;
    #pragma unroll
    for (int off = 1; off < 64; off <<= 1) {
      int u = __shfl_up(incl, off, 64);
      if (lane >= off) incl += u;
    }
    if (lane == 63) wsum[wid] = incl;
    __syncthreads();
    if (wid == 0) {
      int wv = (lane < 16) ? wsum[lane] : 0;
      int wincl = wv;
      #pragma unroll
      for (int off = 1; off < 16; off <<= 1) {
        int u = __shfl_up(wincl, off, 64);
        if (lane >= off) wincl += u;
      }
      if (lane < 16) wsum[lane] = wincl - wv;
    }
    __syncthreads();
    int excl = incl - v + wsum[wid] + carry_s;
    if (idx < NNODES) { start[idx] = excl; cursor[idx] = excl; }
    __syncthreads();
    if (t == 1023) carry_s = excl + v;
    __syncthreads();
  }
  if (t == 0) start[NNODES] = carry_s;
}

// ---------------------------------------------------- CSR build: fill order
__global__ __launch_bounds__(256) void kfill(const int* __restrict__ esrc,
                                             int* __restrict__ cursor,
                                             int* __restrict__ order) {
  int e = blockIdx.x * 256 + threadIdx.x;
  if (e < NE) {
    int p = atomicAdd(&cursor[esrc[e]], 1);
    order[p] = e;
  }
}

// ------------- kprep: split weights (scale folded) into fragment-linear planes
// big weights: group gi = ((kc5*8 + c16)*4 + l4)*16 + l15, elems j=0..7:
//   k = kc5*32 + l4*8 + j, n = c16*16 + l15
__global__ __launch_bounds__(256) void kprep(
    const float* __restrict__ W2a, const float* __restrict__ W2b,
    const float* __restrict__ W2c, const float* __restrict__ Wlin,
    unsigned short* __restrict__ wp)
{
  int tid = blockIdx.x * 256 + threadIdx.x;
  if (tid < 7168) {
    int gi = tid;
    const float* W; float sc; unsigned short* outh; int K;
    if (gi < 3072)      { W = W2a; sc = 0.07216878364870323f; outh = wp + W2A_H; K = 192; }
    else if (gi < 5120) { W = W2b; sc = 0.08838834764831845f; outh = wp + W2B_H; K = 128; gi -= 3072; }
    else                { W = W2c; sc = 0.08838834764831845f; outh = wp + W2C_H; K = 128; gi -= 5120; }
    unsigned short* outl = outh + K * 128;
    int l15 = gi & 15, l4 = (gi >> 4) & 3, c16 = (gi >> 6) & 7, kc5 = gi >> 9;
    #pragma unroll
    for (int j = 0; j < 8; ++j) {
      int k = kc5 * 32 + l4 * 8 + j;
      int n = c16 * 16 + l15;
      float v = W[(size_t)k * 128 + n] * sc;
      unsigned short h = f2bf(v);
      outh[gi * 8 + j] = h;
      outl[gi * 8 + j] = f2bf(v - bf2f(h));
    }
  } else if (tid < 7424) {
    int gi = tid - 7168;  // (((kc2*2+nt)*4+l4)*16+l15)
    int l15 = gi & 15, l4 = (gi >> 4) & 3, nt = (gi >> 6) & 1, kc2 = gi >> 7;
    #pragma unroll
    for (int j = 0; j < 8; ++j) {
      int k = kc2 * 32 + l4 * 8 + j;
      int n = nt * 16 + l15;
      float v = Wlin[(size_t)k * 32 + n] * 0.125f;
      unsigned short h = f2bf(v);
      wp[WLIN_H + gi * 8 + j] = h;
      wp[WLIN_L + gi * 8 + j] = f2bf(v - bf2f(h));
    }
  }
}

// ----------------------------- k1w: w = x@W1/sqrt(128) -> wbuf (no atomics)
__global__ __launch_bounds__(256) void k1w(
    const float* __restrict__ x, const float* __restrict__ W1,
    float* __restrict__ wbuf)
{
  __shared__ __align__(16) float W1s[128 * 32];
  __shared__ __align__(16) float xs[32][128];
  const int t = threadIdx.x;
  const int e0 = blockIdx.x * 32;

  for (int i = t; i < 1024; i += 256)
    *(float4*)&W1s[i * 4] = *(const float4*)&W1[i * 4];
  for (int i = t; i < 1024; i += 256) {
    int row = i >> 5, c = (i & 31) * 4;
    *(float4*)&xs[row][c] = *(const float4*)&x[(size_t)(e0 + row) * 128 + c];
  }
  __syncthreads();

  const int u = t & 31;
  const int es0 = t >> 5;
  float w[4] = {0.f, 0.f, 0.f, 0.f};
  #pragma unroll
  for (int k = 0; k < 128; k += 4) {
    float w0 = W1s[(k + 0) * 32 + u];
    float w1 = W1s[(k + 1) * 32 + u];
    float w2 = W1s[(k + 2) * 32 + u];
    float w3 = W1s[(k + 3) * 32 + u];
    #pragma unroll
    for (int j = 0; j < 4; ++j) {
      float4 xv = *(const float4*)&xs[es0 + j * 8][k];
      w[j] += xv.x * w0 + xv.y * w1 + xv.z * w2 + xv.w * w3;
    }
  }
  #pragma unroll
  for (int j = 0; j < 4; ++j) {
    int e = es0 + j * 8;
    wbuf[(size_t)(e0 + e) * 32 + u] = w[j] * 0.08838834764831845f;
  }
}

// ------------------- k_agg: per-node gather reduction (1 wave per node)
__global__ __launch_bounds__(64) void k_agg(
    const float* __restrict__ wbuf, const float* __restrict__ Y,
    const int* __restrict__ start, const int* __restrict__ order,
    float* __restrict__ agg)
{
  const int n = blockIdx.x;
  const int t = threadIdx.x;
  const int c = t & 31;
  const int dh = t >> 5;
  const int s0 = start[n], s1 = start[n + 1];
  float a0 = 0.f, a1 = 0.f;
  for (int i = s0; i < s1; ++i) {
    int e = order[i];
    float wv = wbuf[(size_t)e * 32 + c];
    float y0 = Y[e * 4 + dh * 2 + 0];
    float y1 = Y[e * 4 + dh * 2 + 1];
    a0 += wv * y0;
    a1 += wv * y1;
  }
  float* ap = agg + (size_t)n * 128 + c * 4 + dh * 2;
  ap[0] = a0;
  ap[1] = a1;
}

// =================== fused: mix + vout + 3-stage MLP + env ===================
// LDS: one 34816 B region. Phase A/stage1: scal packed u32 [128][68].
// Stages 1->2->3: Hs bf16 [128][128] linear + XOR swizzle (byte ^= (row&7)<<4).
__global__ __launch_bounds__(256) void kfused(
    const float* __restrict__ x, const float* __restrict__ V,
    const float* __restrict__ r, const int* __restrict__ esrc,
    const float* __restrict__ agg, const unsigned short* __restrict__ wp,
    float* __restrict__ xout, float* __restrict__ vout)
{
  __shared__ __align__(16) unsigned int smem[128 * 68];  // 34816 B
  unsigned short* Hs = (unsigned short*)smem;

  const int t = threadIdx.x;
  const int w = t >> 6, lane = t & 63;
  const int wr = w >> 1, wc = w & 1;
  const int l15 = lane & 15, l4 = lane >> 4;
  const int e0 = blockIdx.x * 128;

  // ---------------- phase A: tensor-product mix (scal -> LDS, vout -> global)
  {
    short8 WhF[2][2], WlF[2][2];
    #pragma unroll
    for (int kc2 = 0; kc2 < 2; ++kc2)
      #pragma unroll
      for (int nt = 0; nt < 2; ++nt) {
        int idx = ((((kc2 * 2 + nt) * 4 + l4) * 16) + l15) * 8;
        WhF[kc2][nt] = *(const short8*)&wp[WLIN_H + idx];
        WlF[kc2][nt] = *(const short8*)&wp[WLIN_L + idx];
      }

    #pragma unroll
    for (int pass = 0; pass < 2; ++pass) {
      const int er = w * 32 + pass * 16 + l15;
      const int e = e0 + er;
      const int src = esrc[e];
      f32x4 accv[3][2];
      #pragma unroll
      for (int i = 0; i < 3; ++i)
        #pragma unroll
        for (int nt = 0; nt < 2; ++nt) accv[i][nt] = (f32x4)(0.f);

      #pragma unroll
      for (int kc2 = 0; kc2 < 2; ++kc2) {
        float4 av4[4], bv4[4];
        const float* ap = agg + (size_t)src * 128 + kc2 * 64 + l4 * 16;
        const float* bp = V + (size_t)e * 128 + kc2 * 64 + l4 * 16;
        #pragma unroll
        for (int j = 0; j < 4; ++j) {
          av4[j] = *(const float4*)(ap + j * 4);
          bv4[j] = *(const float4*)(bp + j * 4);
          av4[j].x *= 0.25f; av4[j].y *= 0.25f; av4[j].z *= 0.25f; av4[j].w *= 0.25f;
        }
        unsigned int sp[8];
        #pragma unroll
        for (int ch = 0; ch < 4; ++ch) {
          float s1 = av4[ch].x * bv4[ch].x;
          float s2 = (av4[ch].y * bv4[ch].y + av4[ch].z * bv4[ch].z +
                      av4[ch].w * bv4[ch].w) * 0.5773502691896258f;
          sp[2 * ch] = packhl(s1);
          sp[2 * ch + 1] = packhl(s2);
        }
        *(uint4*)&smem[er * 68 + kc2 * 32 + l4 * 8] = *(uint4*)&sp[0];
        *(uint4*)&smem[er * 68 + kc2 * 32 + l4 * 8 + 4] = *(uint4*)&sp[4];

        #pragma unroll
        for (int i = 0; i < 3; ++i) {
          short8 ah, al;
          #pragma unroll
          for (int ch = 0; ch < 4; ++ch) {
            float bvi = (i == 0) ? bv4[ch].y : (i == 1) ? bv4[ch].z : bv4[ch].w;
            float avi = (i == 0) ? av4[ch].y : (i == 1) ? av4[ch].z : av4[ch].w;
            float p0 = av4[ch].x * bvi;
            float p1 = avi * bv4[ch].x;
            unsigned short h0 = f2bf(p0), h1 = f2bf(p1);
            ah[2 * ch] = (short)h0;
            ah[2 * ch + 1] = (short)h1;
            al[2 * ch] = (short)f2bf(p0 - bf2f(h0));
            al[2 * ch + 1] = (short)f2bf(p1 - bf2f(h1));
          }
          #pragma unroll
          for (int nt = 0; nt < 2; ++nt) {
            accv[i][nt] = __builtin_amdgcn_mfma_f32_16x16x32_bf16(ah, WhF[kc2][nt], accv[i][nt], 0, 0, 0);
            accv[i][nt] = __builtin_amdgcn_mfma_f32_16x16x32_bf16(ah, WlF[kc2][nt], accv[i][nt], 0, 0, 0);
            accv[i][nt] = __builtin_amdgcn_mfma_f32_16x16x32_bf16(al, WhF[kc2][nt], accv[i][nt], 0, 0, 0);
          }
        }
      }
      const int ebase = e0 + w * 32 + pass * 16 + l4 * 4;
      #pragma unroll
      for (int nt = 0; nt < 2; ++nt)
        #pragma unroll
        for (int rr = 0; rr < 4; ++rr) {
          float* vp = vout + (size_t)(ebase + rr) * 96 + (nt * 16 + l15) * 3;
          vp[0] = accv[0][nt][rr];
          vp[1] = accv[1][nt][rr];
          vp[2] = accv[2][nt][rr];
        }
    }
  }

  __syncthreads();  // scal visible to all waves

  f32x4 acc[4][4];
  const int c16 = wc * 4;  // wave's B column-tile base

  // ---------------- stage 1: h1 = silu(concat(x, scal) @ W2a / sqrt(192))
  #pragma unroll
  for (int i = 0; i < 4; ++i)
    #pragma unroll
    for (int j = 0; j < 4; ++j) acc[i][j] = (f32x4)(0.f);

  #pragma unroll
  for (int kc = 0; kc < 192; kc += 32) {
    const int kc5 = kc >> 5;
    short8 bh[4], bl[4];
    #pragma unroll
    for (int nf = 0; nf < 4; ++nf) {
      int idx = (((kc5 * 8 + c16 + nf) * 4 + l4) * 16 + l15) * 8;
      bh[nf] = *(const short8*)&wp[W2A_H + idx];
      bl[nf] = *(const short8*)&wp[W2A_L + idx];
    }
    if (kc < 128) {
      #pragma unroll
      for (int mf = 0; mf < 4; ++mf) {
        const float* xp = x + (size_t)(e0 + wr * 64 + mf * 16 + l15) * 128 + kc + l4 * 8;
        float a8[8];
        *(float4*)&a8[0] = *(const float4*)xp;
        *(float4*)&a8[4] = *(const float4*)(xp + 4);
        short8 ah, al;
        split8(a8, ah, al);
        #pragma unroll
        for (int nf = 0; nf < 4; ++nf) {
          acc[mf][nf] = __builtin_amdgcn_mfma_f32_16x16x32_bf16(ah, bh[nf], acc[mf][nf], 0, 0, 0);
          acc[mf][nf] = __builtin_amdgcn_mfma_f32_16x16x32_bf16(ah, bl[nf], acc[mf][nf], 0, 0, 0);
          acc[mf][nf] = __builtin_amdgcn_mfma_f32_16x16x32_bf16(al, bh[nf], acc[mf][nf], 0, 0, 0);
        }
      }
    } else {
      #pragma unroll
      for (int mf = 0; mf < 4; ++mf) {
        int ar = wr * 64 + mf * 16 + l15;
        uint4 q0 = *(const uint4*)&smem[ar * 68 + (kc - 128) + l4 * 8];
        uint4 q1 = *(const uint4*)&smem[ar * 68 + (kc - 128) + l4 * 8 + 4];
        short8 ah, al;
        unpack8(q0, q1, ah, al);
        #pragma unroll
        for (int nf = 0; nf < 4; ++nf) {
          acc[mf][nf] = __builtin_amdgcn_mfma_f32_16x16x32_bf16(ah, bh[nf], acc[mf][nf], 0, 0, 0);
          acc[mf][nf] = __builtin_amdgcn_mfma_f32_16x16x32_bf16(ah, bl[nf], acc[mf][nf], 0, 0, 0);
          acc[mf][nf] = __builtin_amdgcn_mfma_f32_16x16x32_bf16(al, bh[nf], acc[mf][nf], 0, 0, 0);
        }
      }
    }
  }

  __syncthreads();  // scal fully consumed; safe to overwrite with Hs

  #pragma unroll
  for (int mf = 0; mf < 4; ++mf)
    #pragma unroll
    for (int nf = 0; nf < 4; ++nf)
      #pragma unroll
      for (int rr = 0; rr < 4; ++rr) {
        float z = acc[mf][nf][rr];
        z = z / (1.f + __expf(-z));
        int row = wr * 64 + mf * 16 + l4 * 4 + rr;
        int byte = row * 256 + (wc * 64 + nf * 16 + l15) * 2;
        byte ^= (row & 7) << 4;
        Hs[byte >> 1] = f2bf(z);
      }

  __syncthreads();  // h1 visible

  // ---------------- stage 2: h2 = silu(h1 @ W2b / sqrt(128))
  #pragma unroll
  for (int i = 0; i < 4; ++i)
    #pragma unroll
    for (int j = 0; j < 4; ++j) acc[i][j] = (f32x4)(0.f);

  #pragma unroll
  for (int kc = 0; kc < 128; kc += 32) {
    const int kc5 = kc >> 5;
    short8 bh[4], bl[4];
    #pragma unroll
    for (int nf = 0; nf < 4; ++nf) {
      int idx = (((kc5 * 8 + c16 + nf) * 4 + l4) * 16 + l15) * 8;
      bh[nf] = *(const short8*)&wp[W2B_H + idx];
      bl[nf] = *(const short8*)&wp[W2B_L + idx];
    }
    #pragma unroll
    for (int mf = 0; mf < 4; ++mf) {
      int row = wr * 64 + mf * 16 + l15;
      int byte = row * 256 + (kc + l4 * 8) * 2;
      byte ^= (row & 7) << 4;
      short8 ah = *(const short8*)&Hs[byte >> 1];
      #pragma unroll
      for (int nf = 0; nf < 4; ++nf) {
        acc[mf][nf] = __builtin_amdgcn_mfma_f32_16x16x32_bf16(ah, bh[nf], acc[mf][nf], 0, 0, 0);
        acc[mf][nf] = __builtin_amdgcn_mfma_f32_16x16x32_bf16(ah, bl[nf], acc[mf][nf], 0, 0, 0);
      }
    }
  }

  __syncthreads();  // h1 fully consumed

  #pragma unroll
  for (int mf = 0; mf < 4; ++mf)
    #pragma unroll
    for (int nf = 0; nf < 4; ++nf)
      #pragma unroll
      for (int rr = 0; rr < 4; ++rr) {
        float z = acc[mf][nf][rr];
        z = z / (1.f + __expf(-z));
        int row = wr * 64 + mf * 16 + l4 * 4 + rr;
        int byte = row * 256 + (wc * 64 + nf * 16 + l15) * 2;
        byte ^= (row & 7) << 4;
        Hs[byte >> 1] = f2bf(z);
      }

  __syncthreads();  // h2 visible

  // ---------------- stage 3: x_out = env(d) * (h2 @ W2c / sqrt(128))
  #pragma unroll
  for (int i = 0; i < 4; ++i)
    #pragma unroll
    for (int j = 0; j < 4; ++j) acc[i][j] = (f32x4)(0.f);

  #pragma unroll
  for (int kc = 0; kc < 128; kc += 32) {
    const int kc5 = kc >> 5;
    short8 bh[4], bl[4];
    #pragma unroll
    for (int nf = 0; nf < 4; ++nf) {
      int idx = (((kc5 * 8 + c16 + nf) * 4 + l4) * 16 + l15) * 8;
      bh[nf] = *(const short8*)&wp[W2C_H + idx];
      bl[nf] = *(const short8*)&wp[W2C_L + idx];
    }
    #pragma unroll
    for (int mf = 0; mf < 4; ++mf) {
      int row = wr * 64 + mf * 16 + l15;
      int byte = row * 256 + (kc + l4 * 8) * 2;
      byte ^= (row & 7) << 4;
      short8 ah = *(const short8*)&Hs[byte >> 1];
      #pragma unroll
      for (int nf = 0; nf < 4; ++nf) {
        acc[mf][nf] = __builtin_amdgcn_mfma_f32_16x16x32_bf16(ah, bh[nf], acc[mf][nf], 0, 0, 0);
        acc[mf][nf] = __builtin_amdgcn_mfma_f32_16x16x32_bf16(ah, bl[nf], acc[mf][nf], 0, 0, 0);
      }
    }
  }

  #pragma unroll
  for (int mf = 0; mf < 4; ++mf) {
    float env4[4];
    #pragma unroll
    for (int rr = 0; rr < 4; ++rr) {
      int row = e0 + wr * 64 + mf * 16 + l4 * 4 + rr;
      float rx = r[row * 3 + 0];
      float ry = r[row * 3 + 1];
      float rz = r[row * 3 + 2];
      float d2 = rx * rx + ry * ry + rz * rz;
      float d = (d2 == 0.f) ? 1.f : sqrtf(d2);
      float d3 = d * d * d;
      env4[rr] = (d < 1.f) ? (1.f + d3 * d3 * (-28.f + d * (48.f - 21.f * d))) : 0.f;
    }
    #pragma unroll
    for (int nf = 0; nf < 4; ++nf)
      #pragma unroll
      for (int rr = 0; rr < 4; ++rr) {
        int row = e0 + wr * 64 + mf * 16 + l4 * 4 + rr;
        xout[(size_t)row * 128 + wc * 64 + nf * 16 + l15] = acc[mf][nf][rr] * env4[rr];
      }
  }
}

extern "C" void kernel_launch(void* const* d_in, const int* in_sizes, int n_in,
                              void* d_out, int out_size, void* d_ws, size_t ws_size,
                              hipStream_t stream)
{
  const float* x    = (const float*)d_in[0];
  const float* V    = (const float*)d_in[1];
  const float* r    = (const float*)d_in[2];
  const float* Y    = (const float*)d_in[3];
  const int*   es   = (const int*)d_in[4];
  const float* W1   = (const float*)d_in[5];
  const float* W2a  = (const float*)d_in[6];
  const float* W2b  = (const float*)d_in[7];
  const float* W2c  = (const float*)d_in[8];
  const float* Wlin = (const float*)d_in[9];

  float* ws   = (float*)d_ws;
  float* agg  = ws;                          // [0, 3.2M)
  float* wbuf = ws + 3200000;                // [3.2M, 16M)
  unsigned short* wp = (unsigned short*)(ws + 20000000);  // 232 KB weight planes
  int*   ci   = (int*)(ws + 28800000);
  int*   cnt    = ci;
  int*   startv = ci + 25000;
  int*   cursor = ci + 50008;
  int*   order  = ci + 75008;
  float* xout = (float*)d_out;
  float* vout = (float*)d_out + 51200000;

  (void)in_sizes; (void)n_in; (void)out_size; (void)ws_size;

  hipMemsetAsync(cnt, 0, NNODES * sizeof(int), stream);
  khist<<<dim3((NE + 255) / 256), 256, 0, stream>>>(es, cnt);
  kscan<<<dim3(1), 1024, 0, stream>>>(cnt, startv, cursor);
  kfill<<<dim3((NE + 255) / 256), 256, 0, stream>>>(es, cursor, order);
  kprep<<<dim3(29), 256, 0, stream>>>(W2a, W2b, W2c, Wlin, wp);
  k1w<<<dim3(NE / 32), 256, 0, stream>>>(x, W1, wbuf);
  k_agg<<<dim3(NNODES), 64, 0, stream>>>(wbuf, Y, startv, order, agg);
  kfused<<<dim3(NE / 128), 256, 0, stream>>>(x, V, r, es, agg, wp, xout, vout);
}

// Round 7
// 496.177 us; speedup vs baseline: 3.1802x; 1.0679x over previous
//
#include <hip/hip_runtime.h>

#define NE 400000
#define NNODES 25000

typedef __attribute__((ext_vector_type(8))) short short8;
typedef __attribute__((ext_vector_type(4))) float f32x4;

// weight-plane ushort offsets inside wp
#define W2A_H 0
#define W2A_L 24576
#define W2B_H 49152
#define W2B_L 65536
#define W2C_H 81920
#define W2C_L 98304
#define WLIN_H 114688
#define WLIN_L 116736

__device__ __forceinline__ unsigned short f2bf(float f) {
  unsigned int u = __float_as_uint(f);
  unsigned int r = u + 0x7fffu + ((u >> 16) & 1u);
  return (unsigned short)(r >> 16);
}
__device__ __forceinline__ float bf2f(unsigned short h) {
  return __uint_as_float(((unsigned int)h) << 16);
}

// ---------------------------------------------------- CSR build: histogram
__global__ __launch_bounds__(256) void khist(const int* __restrict__ esrc,
                                             int* __restrict__ cnt) {
  int e = blockIdx.x * 256 + threadIdx.x;
  if (e < NE) atomicAdd(&cnt[esrc[e]], 1);
}

// ------------------------------------- CSR build: exclusive scan (1 block)
__global__ __launch_bounds__(1024) void kscan(const int* __restrict__ cnt,
                                              int* __restrict__ start,
                                              int* __restrict__ cursor) {
  __shared__ int wsum[16];
  __shared__ int carry_s;
  const int t = threadIdx.x;
  const int lane = t & 63, wid = t >> 6;
  if (t == 0) carry_s = 0;
  __syncthreads();
  for (int base = 0; base < NNODES; base += 1024) {
    int idx = base + t;
    int v = (idx < NNODES) ? cnt[idx] : 0;
    int incl = v;
    #pragma unroll
    for (int off = 1; off < 64; off <<= 1) {
      int u = __shfl_up(incl, off, 64);
      if (lane >= off) incl += u;
    }
    if (lane == 63) wsum[wid] = incl;
    __syncthreads();
    if (wid == 0) {
      int wv = (lane < 16) ? wsum[lane] : 0;
      int wincl = wv;
      #pragma unroll
      for (int off = 1; off < 16; off <<= 1) {
        int u = __shfl_up(wincl, off, 64);
        if (lane >= off) wincl += u;
      }
      if (lane < 16) wsum[lane] = wincl - wv;
    }
    __syncthreads();
    int excl = incl - v + wsum[wid] + carry_s;
    if (idx < NNODES) { start[idx] = excl; cursor[idx] = excl; }
    __syncthreads();
    if (t == 1023) carry_s = excl + v;
    __syncthreads();
  }
  if (t == 0) start[NNODES] = carry_s;
}

// ---------------------------------------------------- CSR build: fill order
__global__ __launch_bounds__(256) void kfill(const int* __restrict__ esrc,
                                             int* __restrict__ cursor,
                                             int* __restrict__ order) {
  int e = blockIdx.x * 256 + threadIdx.x;
  if (e < NE) {
    int p = atomicAdd(&cursor[esrc[e]], 1);
    order[p] = e;
  }
}

// ------------- kprep: split weights (scale folded) into fragment-linear planes
__global__ __launch_bounds__(256) void kprep(
    const float* __restrict__ W2a, const float* __restrict__ W2b,
    const float* __restrict__ W2c, const float* __restrict__ Wlin,
    unsigned short* __restrict__ wp)
{
  int tid = blockIdx.x * 256 + threadIdx.x;
  if (tid < 7168) {
    int gi = tid;
    const float* W; float sc; unsigned short* outh; int K;
    if (gi < 3072)      { W = W2a; sc = 0.07216878364870323f; outh = wp + W2A_H; K = 192; }
    else if (gi < 5120) { W = W2b; sc = 0.08838834764831845f; outh = wp + W2B_H; K = 128; gi -= 3072; }
    else                { W = W2c; sc = 0.08838834764831845f; outh = wp + W2C_H; K = 128; gi -= 5120; }
    unsigned short* outl = outh + K * 128;
    int l15 = gi & 15, l4 = (gi >> 4) & 3, c16 = (gi >> 6) & 7, kc5 = gi >> 9;
    #pragma unroll
    for (int j = 0; j < 8; ++j) {
      int k = kc5 * 32 + l4 * 8 + j;
      int n = c16 * 16 + l15;
      float v = W[(size_t)k * 128 + n] * sc;
      unsigned short h = f2bf(v);
      outh[gi * 8 + j] = h;
      outl[gi * 8 + j] = f2bf(v - bf2f(h));
    }
  } else if (tid < 7424) {
    int gi = tid - 7168;
    int l15 = gi & 15, l4 = (gi >> 4) & 3, nt = (gi >> 6) & 1, kc2 = gi >> 7;
    #pragma unroll
    for (int j = 0; j < 8; ++j) {
      int k = kc2 * 32 + l4 * 8 + j;
      int n = nt * 16 + l15;
      float v = Wlin[(size_t)k * 32 + n] * 0.125f;
      unsigned short h = f2bf(v);
      wp[WLIN_H + gi * 8 + j] = h;
      wp[WLIN_L + gi * 8 + j] = f2bf(v - bf2f(h));
    }
  }
}

// -------- k1w: w = x@W1/sqrt(128) -> wbuf; ALSO emit x hi-bf16 fragment plane
__global__ __launch_bounds__(256) void k1w(
    const float* __restrict__ x, const float* __restrict__ W1,
    float* __restrict__ wbuf, unsigned short* __restrict__ xh)
{
  __shared__ __align__(16) float W1s[128 * 32];
  __shared__ __align__(16) float xs[32][128];
  const int t = threadIdx.x;
  const int e0 = blockIdx.x * 32;

  for (int i = t; i < 1024; i += 256)
    *(float4*)&W1s[i * 4] = *(const float4*)&W1[i * 4];
  for (int i = t; i < 1024; i += 256) {
    int row = i >> 5, c = (i & 31) * 4;
    *(float4*)&xs[row][c] = *(const float4*)&x[(size_t)(e0 + row) * 128 + c];
  }
  __syncthreads();

  const int u = t & 31;
  const int es0 = t >> 5;
  float w[4] = {0.f, 0.f, 0.f, 0.f};
  #pragma unroll
  for (int k = 0; k < 128; k += 4) {
    float w0 = W1s[(k + 0) * 32 + u];
    float w1 = W1s[(k + 1) * 32 + u];
    float w2 = W1s[(k + 2) * 32 + u];
    float w3 = W1s[(k + 3) * 32 + u];
    #pragma unroll
    for (int j = 0; j < 4; ++j) {
      float4 xv = *(const float4*)&xs[es0 + j * 8][k];
      w[j] += xv.x * w0 + xv.y * w1 + xv.z * w2 + xv.w * w3;
    }
  }
  #pragma unroll
  for (int j = 0; j < 4; ++j) {
    int e = es0 + j * 8;
    wbuf[(size_t)(e0 + e) * 32 + u] = w[j] * 0.08838834764831845f;
  }

  // ---- x hi-plane, fragment-linear: [T][kc5][wr][mf][l4][l15][j]
  {
    const size_t T16 = (size_t)(blockIdx.x >> 2) * 16384;
    const int er0 = (blockIdx.x & 3) * 32;
    const int rrow = t >> 3;
    const int er = er0 + rrow;
    const int wrr = er >> 6, mfe = (er >> 4) & 3, l15e = er & 15;
    #pragma unroll
    for (int uu = 0; uu < 2; ++uu) {
      int un = (t & 7) * 2 + uu;          // 0..15
      int kc5 = un >> 2, l4e = un & 3;
      unsigned short tmp[8];
      #pragma unroll
      for (int j = 0; j < 8; ++j)
        tmp[j] = f2bf(xs[rrow][kc5 * 32 + l4e * 8 + j]);
      *(uint4*)&xh[T16 + kc5 * 4096 + wrr * 2048 + mfe * 512 + l4e * 128 + l15e * 8]
          = *(uint4*)tmp;
    }
  }
}

// ------------------- k_agg: per-node gather reduction (1 wave per node)
__global__ __launch_bounds__(64) void k_agg(
    const float* __restrict__ wbuf, const float* __restrict__ Y,
    const int* __restrict__ start, const int* __restrict__ order,
    float* __restrict__ agg)
{
  const int n = blockIdx.x;
  const int t = threadIdx.x;
  const int c = t & 31;
  const int dh = t >> 5;
  const int s0 = start[n], s1 = start[n + 1];
  float a0 = 0.f, a1 = 0.f;
  for (int i = s0; i < s1; ++i) {
    int e = order[i];
    float wv = wbuf[(size_t)e * 32 + c];
    float y0 = Y[e * 4 + dh * 2 + 0];
    float y1 = Y[e * 4 + dh * 2 + 1];
    a0 += wv * y0;
    a1 += wv * y1;
  }
  float* ap = agg + (size_t)n * 128 + c * 4 + dh * 2;
  ap[0] = a0;
  ap[1] = a1;
}

// =================== fused: mix + vout + 3-stage MLP + env ===================
// LDS: one 32 KB region, 256 B rows, XOR swizzle byte ^= (row&7)<<4.
// Phase A writes scal (bf16, bytes [0,128) of each row); stages write h1/h2.
__global__ __launch_bounds__(256) void kfused(
    const unsigned short* __restrict__ xh, const float* __restrict__ V,
    const float* __restrict__ r, const int* __restrict__ esrc,
    const float* __restrict__ agg, const unsigned short* __restrict__ wp,
    float* __restrict__ xout, float* __restrict__ vout)
{
  __shared__ __align__(16) char lds[32768];

  const int t = threadIdx.x;
  const int w = t >> 6, lane = t & 63;
  const int wr = w >> 1, wc = w & 1;
  const int l15 = lane & 15, l4 = lane >> 4;
  const int e0 = blockIdx.x * 128;

  // ---------------- phase A: tensor-product mix (scal -> LDS, vout -> global)
  {
    short8 WhF[2][2], WlF[2][2];
    #pragma unroll
    for (int kc2 = 0; kc2 < 2; ++kc2)
      #pragma unroll
      for (int nt = 0; nt < 2; ++nt) {
        int idx = ((((kc2 * 2 + nt) * 4 + l4) * 16) + l15) * 8;
        WhF[kc2][nt] = *(const short8*)&wp[WLIN_H + idx];
        WlF[kc2][nt] = *(const short8*)&wp[WLIN_L + idx];
      }

    #pragma unroll
    for (int pass = 0; pass < 2; ++pass) {
      const int er = w * 32 + pass * 16 + l15;
      const int e = e0 + er;
      const int src = esrc[e];
      f32x4 accv[3][2];
      #pragma unroll
      for (int i = 0; i < 3; ++i)
        #pragma unroll
        for (int nt = 0; nt < 2; ++nt) accv[i][nt] = (f32x4)(0.f);

      #pragma unroll
      for (int kc2 = 0; kc2 < 2; ++kc2) {
        float4 av4[4], bv4[4];
        const float* ap = agg + (size_t)src * 128 + kc2 * 64 + l4 * 16;
        const float* bp = V + (size_t)e * 128 + kc2 * 64 + l4 * 16;
        #pragma unroll
        for (int j = 0; j < 4; ++j) {
          av4[j] = *(const float4*)(ap + j * 4);
          bv4[j] = *(const float4*)(bp + j * 4);
          av4[j].x *= 0.25f; av4[j].y *= 0.25f; av4[j].z *= 0.25f; av4[j].w *= 0.25f;
        }
        // scalars (bf16 hi only)
        unsigned short sp[8];
        #pragma unroll
        for (int ch = 0; ch < 4; ++ch) {
          float s1 = av4[ch].x * bv4[ch].x;
          float s2 = (av4[ch].y * bv4[ch].y + av4[ch].z * bv4[ch].z +
                      av4[ch].w * bv4[ch].w) * 0.5773502691896258f;
          sp[2 * ch] = f2bf(s1);
          sp[2 * ch + 1] = f2bf(s2);
        }
        {
          int byte = er * 256 + (kc2 * 32 + l4 * 8) * 2;
          byte ^= (er & 7) << 4;
          *(uint4*)(lds + byte) = *(uint4*)sp;
        }
        // vector products, 2-product MFMA
        #pragma unroll
        for (int i = 0; i < 3; ++i) {
          short8 ah;
          #pragma unroll
          for (int ch = 0; ch < 4; ++ch) {
            float bvi = (i == 0) ? bv4[ch].y : (i == 1) ? bv4[ch].z : bv4[ch].w;
            float avi = (i == 0) ? av4[ch].y : (i == 1) ? av4[ch].z : av4[ch].w;
            ah[2 * ch] = (short)f2bf(av4[ch].x * bvi);      // v1 = a_s*b_v
            ah[2 * ch + 1] = (short)f2bf(avi * bv4[ch].x);  // v2 = a_v*b_s
          }
          #pragma unroll
          for (int nt = 0; nt < 2; ++nt) {
            accv[i][nt] = __builtin_amdgcn_mfma_f32_16x16x32_bf16(ah, WhF[kc2][nt], accv[i][nt], 0, 0, 0);
            accv[i][nt] = __builtin_amdgcn_mfma_f32_16x16x32_bf16(ah, WlF[kc2][nt], accv[i][nt], 0, 0, 0);
          }
        }
      }
      const int ebase = e0 + w * 32 + pass * 16 + l4 * 4;
      #pragma unroll
      for (int nt = 0; nt < 2; ++nt)
        #pragma unroll
        for (int rr = 0; rr < 4; ++rr) {
          float* vp = vout + (size_t)(ebase + rr) * 96 + (nt * 16 + l15) * 3;
          vp[0] = accv[0][nt][rr];
          vp[1] = accv[1][nt][rr];
          vp[2] = accv[2][nt][rr];
        }
    }
  }

  __syncthreads();  // scal visible to all waves

  f32x4 acc[4][4];
  const int c16 = wc * 4;
  const size_t T16 = (size_t)blockIdx.x * 16384;

  // ---------------- stage 1: h1 = silu(concat(x, scal) @ W2a / sqrt(192))
  #pragma unroll
  for (int i = 0; i < 4; ++i)
    #pragma unroll
    for (int j = 0; j < 4; ++j) acc[i][j] = (f32x4)(0.f);

  #pragma unroll
  for (int kc = 0; kc < 192; kc += 32) {
    const int kc5 = kc >> 5;
    short8 bh[4], bl[4];
    #pragma unroll
    for (int nf = 0; nf < 4; ++nf) {
      int idx = (((kc5 * 8 + c16 + nf) * 4 + l4) * 16 + l15) * 8;
      bh[nf] = *(const short8*)&wp[W2A_H + idx];
      bl[nf] = *(const short8*)&wp[W2A_L + idx];
    }
    if (kc < 128) {
      #pragma unroll
      for (int mf = 0; mf < 4; ++mf) {
        short8 ah = *(const short8*)&xh[T16 + kc5 * 4096 + wr * 2048 + mf * 512 + lane * 8];
        #pragma unroll
        for (int nf = 0; nf < 4; ++nf) {
          acc[mf][nf] = __builtin_amdgcn_mfma_f32_16x16x32_bf16(ah, bh[nf], acc[mf][nf], 0, 0, 0);
          acc[mf][nf] = __builtin_amdgcn_mfma_f32_16x16x32_bf16(ah, bl[nf], acc[mf][nf], 0, 0, 0);
        }
      }
    } else {
      #pragma unroll
      for (int mf = 0; mf < 4; ++mf) {
        int ar = wr * 64 + mf * 16 + l15;
        int byte = ar * 256 + ((kc - 128) + l4 * 8) * 2;
        byte ^= (ar & 7) << 4;
        short8 ah = *(const short8*)(lds + byte);
        #pragma unroll
        for (int nf = 0; nf < 4; ++nf) {
          acc[mf][nf] = __builtin_amdgcn_mfma_f32_16x16x32_bf16(ah, bh[nf], acc[mf][nf], 0, 0, 0);
          acc[mf][nf] = __builtin_amdgcn_mfma_f32_16x16x32_bf16(ah, bl[nf], acc[mf][nf], 0, 0, 0);
        }
      }
    }
  }

  __syncthreads();  // scal fully consumed

  #pragma unroll
  for (int mf = 0; mf < 4; ++mf)
    #pragma unroll
    for (int nf = 0; nf < 4; ++nf)
      #pragma unroll
      for (int rr = 0; rr < 4; ++rr) {
        float z = acc[mf][nf][rr];
        z = z / (1.f + __expf(-z));
        int row = wr * 64 + mf * 16 + l4 * 4 + rr;
        int byte = row * 256 + (wc * 64 + nf * 16 + l15) * 2;
        byte ^= (row & 7) << 4;
        *(unsigned short*)(lds + byte) = f2bf(z);
      }

  __syncthreads();  // h1 visible

  // ---------------- stage 2: h2 = silu(h1 @ W2b / sqrt(128))
  #pragma unroll
  for (int i = 0; i < 4; ++i)
    #pragma unroll
    for (int j = 0; j < 4; ++j) acc[i][j] = (f32x4)(0.f);

  #pragma unroll
  for (int kc = 0; kc < 128; kc += 32) {
    const int kc5 = kc >> 5;
    short8 bh[4], bl[4];
    #pragma unroll
    for (int nf = 0; nf < 4; ++nf) {
      int idx = (((kc5 * 8 + c16 + nf) * 4 + l4) * 16 + l15) * 8;
      bh[nf] = *(const short8*)&wp[W2B_H + idx];
      bl[nf] = *(const short8*)&wp[W2B_L + idx];
    }
    #pragma unroll
    for (int mf = 0; mf < 4; ++mf) {
      int row = wr * 64 + mf * 16 + l15;
      int byte = row * 256 + (kc + l4 * 8) * 2;
      byte ^= (row & 7) << 4;
      short8 ah = *(const short8*)(lds + byte);
      #pragma unroll
      for (int nf = 0; nf < 4; ++nf) {
        acc[mf][nf] = __builtin_amdgcn_mfma_f32_16x16x32_bf16(ah, bh[nf], acc[mf][nf], 0, 0, 0);
        acc[mf][nf] = __builtin_amdgcn_mfma_f32_16x16x32_bf16(ah, bl[nf], acc[mf][nf], 0, 0, 0);
      }
    }
  }

  __syncthreads();  // h1 fully consumed

  #pragma unroll
  for (int mf = 0; mf < 4; ++mf)
    #pragma unroll
    for (int nf = 0; nf < 4; ++nf)
      #pragma unroll
      for (int rr = 0; rr < 4; ++rr) {
        float z = acc[mf][nf][rr];
        z = z / (1.f + __expf(-z));
        int row = wr * 64 + mf * 16 + l4 * 4 + rr;
        int byte = row * 256 + (wc * 64 + nf * 16 + l15) * 2;
        byte ^= (row & 7) << 4;
        *(unsigned short*)(lds + byte) = f2bf(z);
      }

  __syncthreads();  // h2 visible

  // ---------------- stage 3: x_out = env(d) * (h2 @ W2c / sqrt(128))
  #pragma unroll
  for (int i = 0; i < 4; ++i)
    #pragma unroll
    for (int j = 0; j < 4; ++j) acc[i][j] = (f32x4)(0.f);

  #pragma unroll
  for (int kc = 0; kc < 128; kc += 32) {
    const int kc5 = kc >> 5;
    short8 bh[4], bl[4];
    #pragma unroll
    for (int nf = 0; nf < 4; ++nf) {
      int idx = (((kc5 * 8 + c16 + nf) * 4 + l4) * 16 + l15) * 8;
      bh[nf] = *(const short8*)&wp[W2C_H + idx];
      bl[nf] = *(const short8*)&wp[W2C_L + idx];
    }
    #pragma unroll
    for (int mf = 0; mf < 4; ++mf) {
      int row = wr * 64 + mf * 16 + l15;
      int byte = row * 256 + (kc + l4 * 8) * 2;
      byte ^= (row & 7) << 4;
      short8 ah = *(const short8*)(lds + byte);
      #pragma unroll
      for (int nf = 0; nf < 4; ++nf) {
        acc[mf][nf] = __builtin_amdgcn_mfma_f32_16x16x32_bf16(ah, bh[nf], acc[mf][nf], 0, 0, 0);
        acc[mf][nf] = __builtin_amdgcn_mfma_f32_16x16x32_bf16(ah, bl[nf], acc[mf][nf], 0, 0, 0);
      }
    }
  }

  #pragma unroll
  for (int mf = 0; mf < 4; ++mf) {
    float env4[4];
    #pragma unroll
    for (int rr = 0; rr < 4; ++rr) {
      int row = e0 + wr * 64 + mf * 16 + l4 * 4 + rr;
      float rx = r[row * 3 + 0];
      float ry = r[row * 3 + 1];
      float rz = r[row * 3 + 2];
      float d2 = rx * rx + ry * ry + rz * rz;
      float d = (d2 == 0.f) ? 1.f : sqrtf(d2);
      float d3 = d * d * d;
      env4[rr] = (d < 1.f) ? (1.f + d3 * d3 * (-28.f + d * (48.f - 21.f * d))) : 0.f;
    }
    #pragma unroll
    for (int nf = 0; nf < 4; ++nf)
      #pragma unroll
      for (int rr = 0; rr < 4; ++rr) {
        int row = e0 + wr * 64 + mf * 16 + l4 * 4 + rr;
        xout[(size_t)row * 128 + wc * 64 + nf * 16 + l15] = acc[mf][nf][rr] * env4[rr];
      }
  }
}

extern "C" void kernel_launch(void* const* d_in, const int* in_sizes, int n_in,
                              void* d_out, int out_size, void* d_ws, size_t ws_size,
                              hipStream_t stream)
{
  const float* x    = (const float*)d_in[0];
  const float* V    = (const float*)d_in[1];
  const float* r    = (const float*)d_in[2];
  const float* Y    = (const float*)d_in[3];
  const int*   es   = (const int*)d_in[4];
  const float* W1   = (const float*)d_in[5];
  const float* W2a  = (const float*)d_in[6];
  const float* W2b  = (const float*)d_in[7];
  const float* W2c  = (const float*)d_in[8];
  const float* Wlin = (const float*)d_in[9];

  float* ws   = (float*)d_ws;
  float* agg  = ws;                                        // [0, 3.2M) floats
  float* wbuf = ws + 3200000;                              // [3.2M, 16M)
  unsigned short* xh = (unsigned short*)(ws + 16000000);   // 51.2M ushort = 102.4 MB
  int*   ci   = (int*)(ws + 42000000);
  int*   cnt    = ci;
  int*   startv = ci + 25000;
  int*   cursor = ci + 50008;
  int*   order  = ci + 75008;
  unsigned short* wp = (unsigned short*)(ws + 43000000);   // 232 KB weight planes
  float* xout = (float*)d_out;
  float* vout = (float*)d_out + 51200000;

  (void)in_sizes; (void)n_in; (void)out_size; (void)ws_size;

  hipMemsetAsync(cnt, 0, NNODES * sizeof(int), stream);
  khist<<<dim3((NE + 255) / 256), 256, 0, stream>>>(es, cnt);
  kscan<<<dim3(1), 1024, 0, stream>>>(cnt, startv, cursor);
  kfill<<<dim3((NE + 255) / 256), 256, 0, stream>>>(es, cursor, order);
  kprep<<<dim3(29), 256, 0, stream>>>(W2a, W2b, W2c, Wlin, wp);
  k1w<<<dim3(NE / 32), 256, 0, stream>>>(x, W1, wbuf, xh);
  k_agg<<<dim3(NNODES), 64, 0, stream>>>(wbuf, Y, startv, order, agg);
  kfused<<<dim3(NE / 128), 256, 0, stream>>>(xh, V, r, es, agg, wp, xout, vout);
}